// Round 2
// baseline (1399.938 us; speedup 1.0000x reference)
//
#include <hip/hip_runtime.h>
#include <math.h>
#include <stdint.h>

// Problem constants
// B=4 S=2048 D=1024 N_NEURONS=512 K=8 N_BASIS=32 R=512 H=8 dh=64
// tokens T = 8192

typedef __attribute__((ext_vector_type(4))) float f32x4;
typedef __attribute__((ext_vector_type(8))) short s16x8;
typedef __attribute__((ext_vector_type(4))) short s16x4;

#define DEV __device__ __forceinline__

DEV short f2bf(float f){
  union { float f; unsigned u; } c; c.f = f;
  unsigned u = c.u;
  unsigned r = (u + 0x7fffu + ((u >> 16) & 1u)) >> 16;
  return (short)r;
}

typedef __attribute__((address_space(3))) void lds_vt;
typedef const __attribute__((address_space(1))) void g_vt;
DEV void gload16(const void* g, void* lds){
  __builtin_amdgcn_global_load_lds((g_vt*)g, (lds_vt*)lds, 16, 0, 0);
}

// ---------------- elementwise f32 -> bf16 ----------------
__global__ void k_conv_bf16(const float* __restrict__ in, short* __restrict__ out, int n4){
  int i = blockIdx.x*256 + threadIdx.x;
  if (i >= n4) return;
  float4 v = ((const float4*)in)[i];
  s16x4 o; o[0]=f2bf(v.x); o[1]=f2bf(v.y); o[2]=f2bf(v.z); o[3]=f2bf(v.w);
  ((s16x4*)out)[i] = o;
}

// ---------------- basis [32][1024][512] -> B2t bf16 [16384][1024], col = r*32+n ----------------
__global__ __launch_bounds__(256) void k_conv_basis(const float* __restrict__ basis, short* __restrict__ B2t){
  __shared__ float tile[64][65];
  int tid = threadIdx.x;
  int r0 = blockIdx.x<<6, d0 = blockIdx.y<<6, n = blockIdx.z;
  const float* src = basis + ((size_t)n*1024 + d0)*512 + r0;
  for (int i = tid; i < 4096; i += 256){ int dd = i>>6, rr = i&63; tile[dd][rr] = src[(size_t)dd*512 + rr]; }
  __syncthreads();
  for (int i = tid; i < 4096; i += 256){ int rr = i>>6, dd = i&63;
    B2t[((size_t)(r0+rr)*32 + n)*1024 + d0 + dd] = f2bf(tile[dd][rr]); }
}

// ---------------- router scores f32 GEMM: S[8192][512] = X[8192][1024] @ W[512][1024]^T ----------------
__global__ __launch_bounds__(256) void k_score_gemm(const float* __restrict__ X, const float* __restrict__ W,
                                                    float* __restrict__ S){
  __shared__ float As[64][17];
  __shared__ float Bs[64][17];
  int tid = threadIdx.x;
  int row0 = blockIdx.x<<6, col0 = blockIdx.y<<6;
  int tx = tid & 15, ty = tid >> 4;
  int lr = tid >> 2, lc = (tid & 3) << 2;
  float acc[4][4];
  #pragma unroll
  for (int i=0;i<4;i++)
    #pragma unroll
    for (int j=0;j<4;j++) acc[i][j] = 0.f;
  for (int k0=0;k0<1024;k0+=16){
    float4 a = *(const float4*)(X + (size_t)(row0+lr)*1024 + k0 + lc);
    float4 b = *(const float4*)(W + (size_t)(col0+lr)*1024 + k0 + lc);
    As[lr][lc+0]=a.x; As[lr][lc+1]=a.y; As[lr][lc+2]=a.z; As[lr][lc+3]=a.w;
    Bs[lr][lc+0]=b.x; Bs[lr][lc+1]=b.y; Bs[lr][lc+2]=b.z; Bs[lr][lc+3]=b.w;
    __syncthreads();
    #pragma unroll
    for (int kk=0;kk<16;kk++){
      float a4[4], b4[4];
      #pragma unroll
      for (int i=0;i<4;i++) a4[i] = As[ty*4+i][kk];
      #pragma unroll
      for (int j=0;j<4;j++) b4[j] = Bs[tx*4+j][kk];
      #pragma unroll
      for (int i=0;i<4;i++)
        #pragma unroll
        for (int j=0;j<4;j++) acc[i][j] += a4[i]*b4[j];
    }
    __syncthreads();
  }
  #pragma unroll
  for (int i=0;i<4;i++)
    #pragma unroll
    for (int j=0;j<4;j++)
      S[(size_t)(row0+ty*4+i)*512 + col0 + tx*4 + j] = acc[i][j];
}

// ---------------- router: f32 top-16 candidates -> f64 exact rescore -> top-8 ----------------
__global__ __launch_bounds__(64) void k_router(const float* __restrict__ scores,
    const float* __restrict__ X, const float* __restrict__ W,
    const float* __restrict__ rQ, const float* __restrict__ rK, const float* __restrict__ rV,
    float* __restrict__ tQ, float* __restrict__ tK, float* __restrict__ tV,
    float* __restrict__ oidx, float* __restrict__ ow){
  int token = blockIdx.x; int lane = threadIdx.x;
  const float* srow = scores + (size_t)token*512;
  float v[8];
  #pragma unroll
  for (int j=0;j<8;j++) v[j] = srow[lane + 64*j];
  // ---- stage 1: top-16 candidates by f32 score (margin >> f32 error) ----
  int myidx = 0x7fffffff;     // lane k (k<16) will hold candidate k's neuron id
  #pragma unroll
  for (int k=0;k<16;k++){
    float bm = -INFINITY; int bi = 0x7fffffff;
    #pragma unroll
    for (int j=0;j<8;j++){ if (v[j] > bm) { bm = v[j]; bi = lane + 64*j; } }
    #pragma unroll
    for (int off=32; off>=1; off>>=1){
      float om = __shfl_xor(bm, off); int oi = __shfl_xor(bi, off);
      if (om > bm || (om == bm && oi < bi)) { bm = om; bi = oi; }
    }
    if (lane == k) myidx = bi;
    #pragma unroll
    for (int j=0;j<8;j++) if (lane + 64*j == bi) v[j] = -INFINITY;
  }
  // ---- stage 2: exact f64 rescore of the 16 candidates ----
  float xr[16];
  {
    const float4* x4 = (const float4*)(X + (size_t)token*1024 + lane*16);
    #pragma unroll
    for (int q=0;q<4;q++){ float4 t = x4[q]; xr[q*4]=t.x; xr[q*4+1]=t.y; xr[q*4+2]=t.z; xr[q*4+3]=t.w; }
  }
  double myref = -1e300;
  #pragma unroll
  for (int c=0;c<16;c++){
    int nid = __shfl(myidx, c);
    const float4* w4 = (const float4*)(W + (size_t)nid*1024 + lane*16);
    double acc = 0.0;
    #pragma unroll
    for (int q=0;q<4;q++){
      float4 t = w4[q];
      acc += (double)xr[q*4]   * (double)t.x;
      acc += (double)xr[q*4+1] * (double)t.y;
      acc += (double)xr[q*4+2] * (double)t.z;
      acc += (double)xr[q*4+3] * (double)t.w;
    }
    #pragma unroll
    for (int off=32; off>=1; off>>=1) acc += __shfl_xor(acc, off);
    if (lane == c) myref = acc;
  }
  // ---- stage 3: top-8 over the f64-refined scores ----
  double mv = myref; int mi = myidx;
  double topv[8]; int topi[8];
  #pragma unroll
  for (int k=0;k<8;k++){
    double bm = mv; int bi = mi;
    #pragma unroll
    for (int off=32; off>=1; off>>=1){
      double om = __shfl_xor(bm, off); int oi = __shfl_xor(bi, off);
      if (om > bm || (om == bm && oi < bi)) { bm = om; bi = oi; }
    }
    topv[k]=bm; topi[k]=bi;
    if (mi == bi) mv = -1e300;
  }
  double mx = topv[0]; double s = 0.0; double wd[8];
  #pragma unroll
  for (int k=0;k<8;k++){ wd[k] = exp(topv[k]-mx); s += wd[k]; }
  float w[8];
  #pragma unroll
  for (int k=0;k<8;k++) w[k] = (float)(wd[k]/s);
  if (lane == 0){
    #pragma unroll
    for (int k=0;k<8;k++){ oidx[(size_t)token*8+k] = (float)topi[k]; ow[(size_t)token*8+k] = w[k]; }
  }
  // ---- recipe softmaxes ----
  int n = lane & 31;
  float aq=0.f, ak=0.f, av=0.f;
  #pragma unroll
  for (int k=0;k<8;k++){
    size_t off = (size_t)topi[k]*32 + n;
    aq += w[k]*rQ[off]; ak += w[k]*rK[off]; av += w[k]*rV[off];
  }
  float mq = aq, mk2 = ak, mvv = av;
  #pragma unroll
  for (int off=16; off>=1; off>>=1){
    mq  = fmaxf(mq,  __shfl_xor(mq, off));
    mk2 = fmaxf(mk2, __shfl_xor(mk2,off));
    mvv = fmaxf(mvv, __shfl_xor(mvv,off));
  }
  float eq = expf(aq-mq), ek = expf(ak-mk2), ev = expf(av-mvv);
  float sq = eq, sk = ek, sv = ev;
  #pragma unroll
  for (int off=16; off>=1; off>>=1){
    sq += __shfl_xor(sq,off); sk += __shfl_xor(sk,off); sv += __shfl_xor(sv,off);
  }
  if (lane < 32){
    tQ[(size_t)token*32+n] = eq/sq;
    tK[(size_t)token*32+n] = ek/sk;
    tV[(size_t)token*32+n] = ev/sv;
  }
}

// ---------------- bf16 MFMA GEMM 128x128xBK64: C = A[M][Kd] @ Bt[N][Kd]^T ----------------
// EPI=0: write C f32. EPI=1: fused n-contract epilogue -> Q/K/V bf16 (cols are r*32+n).
template<int EPI>
__global__ __launch_bounds__(256) void k_mfma_gemm(
    const short* __restrict__ A, const short* __restrict__ Bt, int Kd,
    float* __restrict__ C, int ldc,
    const float* __restrict__ tQp, const float* __restrict__ tKp, const float* __restrict__ tVp,
    short* __restrict__ Qb, short* __restrict__ Kb, short* __restrict__ Vb)
{
  __shared__ char smem[EPI ? 49152 : 32768];
  short* Asm = (short*)smem;
  short* Bsm = (short*)(smem + 16384);
  int tid = threadIdx.x, lane = tid & 63, w = tid >> 6;
  int wr = w >> 1, wc = w & 1;
  int row0 = blockIdx.x << 7, col0 = blockIdx.y << 7;
  f32x4 acc[4][4];
  #pragma unroll
  for (int m=0;m<4;m++)
    #pragma unroll
    for (int nf=0;nf<4;nf++)
      #pragma unroll
      for (int e=0;e<4;e++) acc[m][nf][e] = 0.f;
  int lr8 = lane >> 3, lk = (lane & 7) << 3;
  for (int k0 = 0; k0 < Kd; k0 += 64){
    #pragma unroll
    for (int i=0;i<4;i++){
      int chunk = (w<<2) + i;
      int r = (chunk<<3) + lr8;
      gload16(A  + (size_t)(row0 + r)*Kd + k0 + lk, smem + chunk*1024);
      gload16(Bt + (size_t)(col0 + r)*Kd + k0 + lk, smem + 16384 + chunk*1024);
    }
    __syncthreads();
    #pragma unroll
    for (int kk=0; kk<2; kk++){
      s16x8 af[4], bfr[4];
      #pragma unroll
      for (int m=0;m<4;m++)
        af[m] = *(const s16x8*)(Asm + ((wr*64 + m*16 + (lane&15))*64 + kk*32 + ((lane>>4)<<3)));
      #pragma unroll
      for (int nf=0;nf<4;nf++)
        bfr[nf] = *(const s16x8*)(Bsm + ((wc*64 + nf*16 + (lane&15))*64 + kk*32 + ((lane>>4)<<3)));
      #pragma unroll
      for (int m=0;m<4;m++)
        #pragma unroll
        for (int nf=0;nf<4;nf++)
          acc[m][nf] = __builtin_amdgcn_mfma_f32_16x16x32_bf16(af[m], bfr[nf], acc[m][nf], 0, 0, 0);
    }
    __syncthreads();
  }
  if (EPI == 0){
    #pragma unroll
    for (int m=0;m<4;m++)
      #pragma unroll
      for (int nf=0;nf<4;nf++)
        #pragma unroll
        for (int e=0;e<4;e++){
          int tok = wr*64 + m*16 + ((lane>>4)<<2) + e;
          int col = wc*64 + nf*16 + (lane&15);
          C[(size_t)(row0+tok)*ldc + col0 + col] = acc[m][nf][e];
        }
  } else {
    // reuse LDS (all waves past final barrier) for t-weights [3][128][32]
    float* t_lds = (float*)smem;
    for (int i=tid; i<4096; i+=256) t_lds[i]        = tQp[(size_t)row0*32 + i];
    for (int i=tid; i<4096; i+=256) t_lds[4096+i]   = tKp[(size_t)row0*32 + i];
    for (int i=tid; i<4096; i+=256) t_lds[8192+i]   = tVp[(size_t)row0*32 + i];
    __syncthreads();
    int n0 = lane & 15;
    int r_base = (col0 >> 5) + wc*2;
    #pragma unroll
    for (int rec=0; rec<3; rec++){
      const float* tb = t_lds + rec*4096;
      short* op = (rec==0) ? Qb : ((rec==1) ? Kb : Vb);
      #pragma unroll
      for (int m=0;m<4;m++){
        #pragma unroll
        for (int g=0; g<2; g++){
          #pragma unroll
          for (int e=0;e<4;e++){
            int tok = wr*64 + m*16 + ((lane>>4)<<2) + e;
            float vv = acc[m][2*g][e]*tb[tok*32 + n0] + acc[m][2*g+1][e]*tb[tok*32 + 16 + n0];
            #pragma unroll
            for (int off=1; off<16; off<<=1) vv += __shfl_xor(vv, off);
            if (n0 == 0) op[(size_t)(row0+tok)*512 + r_base + g] = f2bf(vv);
          }
        }
      }
    }
  }
}

// ---------------- causal flash attention, 1 wave / 16-row q-tile, dh=64 ----------------
__global__ __launch_bounds__(64) void k_attn(const short* __restrict__ Qb, const short* __restrict__ Kb,
                                             const short* __restrict__ Vb, short* __restrict__ Ob)
{
  __shared__ short Ksm[2048];   // [32 kv][64 d]
  __shared__ short Vtsm[2048];  // [64 d][32 kv]
  __shared__ short Psm[512];    // [16 q][32 kv]
  int lane = threadIdx.x;
  int q0 = blockIdx.x << 4, h = blockIdx.y, b = blockIdx.z;
  size_t base = ((size_t)b*2048)*512 + h*64;
  s16x8 qf[2];
  {
    const short* qp = Qb + base + (size_t)(q0 + (lane&15))*512 + ((lane>>4)<<3);
    qf[0] = *(const s16x8*)(qp);
    qf[1] = *(const s16x8*)(qp + 32);
  }
  f32x4 o[4]; float mrow[4], lrow[4], alpha[4];
  #pragma unroll
  for (int i=0;i<4;i++){
    #pragma unroll
    for (int e=0;e<4;e++) o[i][e]=0.f;
    mrow[i]=-INFINITY; lrow[i]=0.f;
  }
  int kv_end = q0 + 16;
  for (int kv0 = 0; kv0 < kv_end; kv0 += 32){
    #pragma unroll
    for (int j=0;j<4;j++){
      int r = (j<<3) + (lane>>3);
      gload16(Kb + base + (size_t)(kv0 + r)*512 + ((lane&7)<<3), (char*)Ksm + j*1024);
      s16x8 vv = *(const s16x8*)(Vb + base + (size_t)(kv0 + r)*512 + ((lane&7)<<3));
      #pragma unroll
      for (int e=0;e<8;e++) Vtsm[(((lane&7)<<3) + e)*32 + r] = vv[e];
    }
    __syncthreads();
    f32x4 S0, S1;
    #pragma unroll
    for (int e=0;e<4;e++){ S0[e]=0.f; S1[e]=0.f; }
    #pragma unroll
    for (int kk=0;kk<2;kk++){
      s16x8 kf0 = *(const s16x8*)(Ksm + ((lane&15))*64 + kk*32 + ((lane>>4)<<3));
      s16x8 kf1 = *(const s16x8*)(Ksm + (16 + (lane&15))*64 + kk*32 + ((lane>>4)<<3));
      S0 = __builtin_amdgcn_mfma_f32_16x16x32_bf16(qf[kk], kf0, S0, 0,0,0);
      S1 = __builtin_amdgcn_mfma_f32_16x16x32_bf16(qf[kk], kf1, S1, 0,0,0);
    }
    #pragma unroll
    for (int e=0;e<4;e++){
      int q = q0 + ((lane>>4)<<2) + e;
      int kvA = kv0 + (lane&15);
      float s0 = S0[e]*0.125f;
      float s1 = S1[e]*0.125f;
      if (kvA > q)      s0 = -1e30f;
      if (kvA + 16 > q) s1 = -1e30f;
      float tm = fmaxf(s0, s1);
      #pragma unroll
      for (int off=1; off<16; off<<=1) tm = fmaxf(tm, __shfl_xor(tm, off));
      float mnew = fmaxf(mrow[e], tm);
      alpha[e] = expf(mrow[e] - mnew);
      float p0 = expf(s0 - mnew), p1 = expf(s1 - mnew);
      float ps = p0 + p1;
      #pragma unroll
      for (int off=1; off<16; off<<=1) ps += __shfl_xor(ps, off);
      lrow[e] = lrow[e]*alpha[e] + ps;
      mrow[e] = mnew;
      int prow = ((lane>>4)<<2) + e;
      Psm[prow*32 + (lane&15)]      = f2bf(p0);
      Psm[prow*32 + 16 + (lane&15)] = f2bf(p1);
    }
    __syncthreads();
    s16x8 pf = *(const s16x8*)(Psm + (lane&15)*32 + ((lane>>4)<<3));
    #pragma unroll
    for (int df=0; df<4; df++){
      s16x8 vf = *(const s16x8*)(Vtsm + (df*16 + (lane&15))*32 + ((lane>>4)<<3));
      f32x4 t;
      #pragma unroll
      for (int e=0;e<4;e++) t[e] = o[df][e]*alpha[e];
      o[df] = __builtin_amdgcn_mfma_f32_16x16x32_bf16(pf, vf, t, 0,0,0);
    }
    __syncthreads();
  }
  #pragma unroll
  for (int df=0; df<4; df++)
    #pragma unroll
    for (int e=0;e<4;e++){
      int q = q0 + ((lane>>4)<<2) + e;
      int d = df*16 + (lane&15);
      Ob[base + (size_t)q*512 + d] = f2bf(o[df][e] / lrow[e]);
    }
}

extern "C" void kernel_launch(void* const* d_in, const int* in_sizes, int n_in,
                              void* d_out, int out_size, void* d_ws, size_t ws_size,
                              hipStream_t stream)
{
  const float* x     = (const float*)d_in[0];
  const float* Wrt   = (const float*)d_in[1];
  const float* rQ    = (const float*)d_in[2];
  const float* rK    = (const float*)d_in[3];
  const float* rV    = (const float*)d_in[4];
  const float* basis = (const float*)d_in[5];
  const float* Wo    = (const float*)d_in[6];
  // d_in[7] = mask (causal tril; reproduced analytically)
  float* out = (float*)d_out;
  char* ws = (char*)d_ws;
  short* B2t = (short*)(ws + 0);          // 32 MB  [16384][1024] bf16
  short* Xb  = (short*)(ws + 33554432);   // 16 MB  [8192][1024]  bf16
  float* SC  = (float*)(ws + 50331648);   // 16 MB  [8192][512]   f32
  float* tQ  = (float*)(ws + 67108864);   // 1 MB
  float* tK  = (float*)(ws + 68157440);   // 1 MB
  float* tV  = (float*)(ws + 69206016);   // 1 MB
  short* Qb  = (short*)(ws + 70254592);   // 8 MB   [8192][512] bf16
  short* Kb  = (short*)(ws + 78643200);   // 8 MB
  short* Vb  = (short*)(ws + 87031808);   // 8 MB
  short* Ob  = (short*)(ws + 95420416);   // 8 MB
  short* Wob = (short*)(ws + 103809024);  // 1 MB   [1024][512] bf16
  float* oidx = out + 8388608;
  float* oww  = out + 8454144;

  k_conv_bf16<<<8192, 256, 0, stream>>>(x, Xb, 2097152);
  k_conv_bf16<<<512, 256, 0, stream>>>(Wo, Wob, 131072);
  k_conv_basis<<<dim3(8,16,32), 256, 0, stream>>>(basis, B2t);
  k_score_gemm<<<dim3(128,8), 256, 0, stream>>>(x, Wrt, SC);
  k_router<<<8192, 64, 0, stream>>>(SC, x, Wrt, rQ, rK, rV, tQ, tK, tV, oidx, oww);
  k_mfma_gemm<1><<<dim3(64,128), 256, 0, stream>>>(Xb, B2t, 1024, nullptr, 0,
                                                   tQ, tK, tV, Qb, Kb, Vb);
  k_attn<<<dim3(128,8,4), 64, 0, stream>>>(Qb, Kb, Vb, Ob);
  k_mfma_gemm<0><<<dim3(64,8), 256, 0, stream>>>(Ob, Wob, 512, out, 1024,
                                                 nullptr, nullptr, nullptr, nullptr, nullptr, nullptr);
}

// Round 3
// 1332.957 us; speedup vs baseline: 1.0503x; 1.0503x over previous
//
#include <hip/hip_runtime.h>
#include <math.h>
#include <stdint.h>

// Problem constants
// B=4 S=2048 D=1024 N_NEURONS=512 K=8 N_BASIS=32 R=512 H=8 dh=64
// tokens T = 8192

typedef __attribute__((ext_vector_type(4))) float f32x4;
typedef __attribute__((ext_vector_type(8))) short s16x8;
typedef __attribute__((ext_vector_type(4))) short s16x4;

#define DEV __device__ __forceinline__

DEV short f2bf(float f){
  union { float f; unsigned u; } c; c.f = f;
  unsigned u = c.u;
  unsigned r = (u + 0x7fffu + ((u >> 16) & 1u)) >> 16;
  return (short)r;
}
DEV float bf2f(short s){
  union { unsigned u; float f; } c; c.u = ((unsigned)(unsigned short)s) << 16;
  return c.f;
}

typedef __attribute__((address_space(3))) void lds_vt;
typedef const __attribute__((address_space(1))) void g_vt;
DEV void gload16(const void* g, void* lds){
  __builtin_amdgcn_global_load_lds((g_vt*)g, (lds_vt*)lds, 16, 0, 0);
}

// ---------------- elementwise f32 -> bf16 ----------------
__global__ void k_conv_bf16(const float* __restrict__ in, short* __restrict__ out, int n4){
  int i = blockIdx.x*256 + threadIdx.x;
  if (i >= n4) return;
  float4 v = ((const float4*)in)[i];
  s16x4 o; o[0]=f2bf(v.x); o[1]=f2bf(v.y); o[2]=f2bf(v.z); o[3]=f2bf(v.w);
  ((s16x4*)out)[i] = o;
}

// ---------------- basis [32][1024][512] -> B2t bf16 [16384][1024], col = r*32+n ----------------
__global__ __launch_bounds__(256) void k_conv_basis(const float* __restrict__ basis, short* __restrict__ B2t){
  __shared__ float tile[64][65];
  int tid = threadIdx.x;
  int r0 = blockIdx.x<<6, d0 = blockIdx.y<<6, n = blockIdx.z;
  const float* src = basis + ((size_t)n*1024 + d0)*512 + r0;
  for (int i = tid; i < 4096; i += 256){ int dd = i>>6, rr = i&63; tile[dd][rr] = src[(size_t)dd*512 + rr]; }
  __syncthreads();
  for (int i = tid; i < 4096; i += 256){ int rr = i>>6, dd = i&63;
    B2t[((size_t)(r0+rr)*32 + n)*1024 + d0 + dd] = f2bf(tile[dd][rr]); }
}

// ---------------- router scores f32 GEMM: S[8192][512] = X[8192][1024] @ W[512][1024]^T ----------------
__global__ __launch_bounds__(256) void k_score_gemm(const float* __restrict__ X, const float* __restrict__ W,
                                                    float* __restrict__ S){
  __shared__ float As[64][17];
  __shared__ float Bs[64][17];
  int tid = threadIdx.x;
  int row0 = blockIdx.x<<6, col0 = blockIdx.y<<6;
  int tx = tid & 15, ty = tid >> 4;
  int lr = tid >> 2, lc = (tid & 3) << 2;
  float acc[4][4];
  #pragma unroll
  for (int i=0;i<4;i++)
    #pragma unroll
    for (int j=0;j<4;j++) acc[i][j] = 0.f;
  for (int k0=0;k0<1024;k0+=16){
    float4 a = *(const float4*)(X + (size_t)(row0+lr)*1024 + k0 + lc);
    float4 b = *(const float4*)(W + (size_t)(col0+lr)*1024 + k0 + lc);
    As[lr][lc+0]=a.x; As[lr][lc+1]=a.y; As[lr][lc+2]=a.z; As[lr][lc+3]=a.w;
    Bs[lr][lc+0]=b.x; Bs[lr][lc+1]=b.y; Bs[lr][lc+2]=b.z; Bs[lr][lc+3]=b.w;
    __syncthreads();
    #pragma unroll
    for (int kk=0;kk<16;kk++){
      float a4[4], b4[4];
      #pragma unroll
      for (int i=0;i<4;i++) a4[i] = As[ty*4+i][kk];
      #pragma unroll
      for (int j=0;j<4;j++) b4[j] = Bs[tx*4+j][kk];
      #pragma unroll
      for (int i=0;i<4;i++)
        #pragma unroll
        for (int j=0;j<4;j++) acc[i][j] += a4[i]*b4[j];
    }
    __syncthreads();
  }
  #pragma unroll
  for (int i=0;i<4;i++)
    #pragma unroll
    for (int j=0;j<4;j++)
      S[(size_t)(row0+ty*4+i)*512 + col0 + tx*4 + j] = acc[i][j];
}

// ---------------- router: f32 top-16 candidates -> f64 exact rescore -> top-8 ----------------
__global__ __launch_bounds__(64) void k_router(const float* __restrict__ scores,
    const float* __restrict__ X, const float* __restrict__ W,
    const float* __restrict__ rQ, const float* __restrict__ rK, const float* __restrict__ rV,
    float* __restrict__ tQ, float* __restrict__ tK, float* __restrict__ tV,
    float* __restrict__ oidx, float* __restrict__ ow){
  int token = blockIdx.x; int lane = threadIdx.x;
  const float* srow = scores + (size_t)token*512;
  float v[8];
  #pragma unroll
  for (int j=0;j<8;j++) v[j] = srow[lane + 64*j];
  // ---- stage 1: top-16 candidates by f32 score (margin >> f32 error) ----
  int myidx = 0x7fffffff;
  #pragma unroll
  for (int k=0;k<16;k++){
    float bm = -INFINITY; int bi = 0x7fffffff;
    #pragma unroll
    for (int j=0;j<8;j++){ if (v[j] > bm) { bm = v[j]; bi = lane + 64*j; } }
    #pragma unroll
    for (int off=32; off>=1; off>>=1){
      float om = __shfl_xor(bm, off); int oi = __shfl_xor(bi, off);
      if (om > bm || (om == bm && oi < bi)) { bm = om; bi = oi; }
    }
    if (lane == k) myidx = bi;
    #pragma unroll
    for (int j=0;j<8;j++) if (lane + 64*j == bi) v[j] = -INFINITY;
  }
  // ---- stage 2: exact f64 rescore of the 16 candidates ----
  float xr[16];
  {
    const float4* x4 = (const float4*)(X + (size_t)token*1024 + lane*16);
    #pragma unroll
    for (int q=0;q<4;q++){ float4 t = x4[q]; xr[q*4]=t.x; xr[q*4+1]=t.y; xr[q*4+2]=t.z; xr[q*4+3]=t.w; }
  }
  double myref = -1e300;
  #pragma unroll
  for (int c=0;c<16;c++){
    int nid = __shfl(myidx, c);
    const float4* w4 = (const float4*)(W + (size_t)nid*1024 + lane*16);
    double acc = 0.0;
    #pragma unroll
    for (int q=0;q<4;q++){
      float4 t = w4[q];
      acc += (double)xr[q*4]   * (double)t.x;
      acc += (double)xr[q*4+1] * (double)t.y;
      acc += (double)xr[q*4+2] * (double)t.z;
      acc += (double)xr[q*4+3] * (double)t.w;
    }
    #pragma unroll
    for (int off=32; off>=1; off>>=1) acc += __shfl_xor(acc, off);
    if (lane == c) myref = acc;
  }
  // ---- stage 3: top-8 over the f64-refined scores ----
  double mv = myref; int mi = myidx;
  double topv[8]; int topi[8];
  #pragma unroll
  for (int k=0;k<8;k++){
    double bm = mv; int bi = mi;
    #pragma unroll
    for (int off=32; off>=1; off>>=1){
      double om = __shfl_xor(bm, off); int oi = __shfl_xor(bi, off);
      if (om > bm || (om == bm && oi < bi)) { bm = om; bi = oi; }
    }
    topv[k]=bm; topi[k]=bi;
    if (mi == bi) mv = -1e300;
  }
  double mx = topv[0]; double s = 0.0; double wd[8];
  #pragma unroll
  for (int k=0;k<8;k++){ wd[k] = exp(topv[k]-mx); s += wd[k]; }
  float w[8];
  #pragma unroll
  for (int k=0;k<8;k++) w[k] = (float)(wd[k]/s);
  if (lane == 0){
    #pragma unroll
    for (int k=0;k<8;k++){ oidx[(size_t)token*8+k] = (float)topi[k]; ow[(size_t)token*8+k] = w[k]; }
  }
  // ---- recipe softmaxes ----
  int n = lane & 31;
  float aq=0.f, ak=0.f, av=0.f;
  #pragma unroll
  for (int k=0;k<8;k++){
    size_t off = (size_t)topi[k]*32 + n;
    aq += w[k]*rQ[off]; ak += w[k]*rK[off]; av += w[k]*rV[off];
  }
  float mq = aq, mk2 = ak, mvv = av;
  #pragma unroll
  for (int off=16; off>=1; off>>=1){
    mq  = fmaxf(mq,  __shfl_xor(mq, off));
    mk2 = fmaxf(mk2, __shfl_xor(mk2,off));
    mvv = fmaxf(mvv, __shfl_xor(mvv,off));
  }
  float eq = expf(aq-mq), ek = expf(ak-mk2), ev = expf(av-mvv);
  float sq = eq, sk = ek, sv = ev;
  #pragma unroll
  for (int off=16; off>=1; off>>=1){
    sq += __shfl_xor(sq,off); sk += __shfl_xor(sk,off); sv += __shfl_xor(sv,off);
  }
  if (lane < 32){
    tQ[(size_t)token*32+n] = eq/sq;
    tK[(size_t)token*32+n] = ek/sk;
    tV[(size_t)token*32+n] = ev/sv;
  }
}

// ---------------- bf16 MFMA GEMM 128x128xBK64, T2-swizzled LDS, XCD-swizzled grid ----------------
// C = A[M][Kd] @ Bt[N][Kd]^T. 1-D grid, nwg % 8 == 0.
// EPI=0: write C f32. EPI=1: fused n-contract epilogue -> Q/K/V bf16 (cols are r*32+n).
template<int EPI>
__global__ __launch_bounds__(256) void k_mfma_gemm(
    const short* __restrict__ A, const short* __restrict__ Bt, int Kd, int Mblk,
    float* __restrict__ C, int ldc,
    const float* __restrict__ tQp, const float* __restrict__ tKp, const float* __restrict__ tVp,
    short* __restrict__ Qb, short* __restrict__ Kb, short* __restrict__ Vb)
{
  __shared__ char smem[32768];
  short* Asm = (short*)smem;
  short* Bsm = (short*)(smem + 16384);
  int tid = threadIdx.x, lane = tid & 63, w = tid >> 6;
  int wr = w >> 1, wc = w & 1;
  // XCD-aware bijective swizzle: each XCD gets a contiguous sid-chunk
  // (Mblk consecutive rows x nwg/(8*Mblk) cols -> B-panels map 1:1 to XCDs).
  int nwg = gridDim.x, bid = blockIdx.x;
  int sid = (bid & 7) * (nwg >> 3) + (bid >> 3);
  int row0 = (sid % Mblk) << 7;
  int col0 = (sid / Mblk) << 7;
  f32x4 acc[4][4];
  #pragma unroll
  for (int m=0;m<4;m++)
    #pragma unroll
    for (int nf=0;nf<4;nf++)
      #pragma unroll
      for (int e=0;e<4;e++) acc[m][nf][e] = 0.f;
  // staging: lane l of chunk c writes LDS row c*8+(l>>3), 16B-granule (l&7).
  // T2 swizzle S: LDS(row, g) holds global(row, g ^ (row&7)) [16B granules].
  int lr8 = lane >> 3;
  int lk_sw = (((lane & 7) ^ (lane >> 3)) << 3);  // bf16 elems, inverse-swizzled source col
  for (int k0 = 0; k0 < Kd; k0 += 64){
    #pragma unroll
    for (int i=0;i<4;i++){
      int chunk = (w<<2) + i;
      int r = (chunk<<3) + lr8;
      gload16(A  + (size_t)(row0 + r)*Kd + k0 + lk_sw, smem + chunk*1024);
      gload16(Bt + (size_t)(col0 + r)*Kd + k0 + lk_sw, smem + 16384 + chunk*1024);
    }
    __syncthreads();
    #pragma unroll
    for (int kk=0; kk<2; kk++){
      int csw = (kk*32 + ((lane>>4)<<3)) ^ ((lane & 7) << 3);  // swizzled read col (bf16)
      s16x8 af[4], bfr[4];
      #pragma unroll
      for (int m=0;m<4;m++)
        af[m] = *(const s16x8*)(Asm + ((wr*64 + m*16 + (lane&15))*64 + csw));
      #pragma unroll
      for (int nf=0;nf<4;nf++)
        bfr[nf] = *(const s16x8*)(Bsm + ((wc*64 + nf*16 + (lane&15))*64 + csw));
      #pragma unroll
      for (int m=0;m<4;m++)
        #pragma unroll
        for (int nf=0;nf<4;nf++)
          acc[m][nf] = __builtin_amdgcn_mfma_f32_16x16x32_bf16(af[m], bfr[nf], acc[m][nf], 0, 0, 0);
    }
    __syncthreads();
  }
  if (EPI == 0){
    #pragma unroll
    for (int m=0;m<4;m++)
      #pragma unroll
      for (int nf=0;nf<4;nf++)
        #pragma unroll
        for (int e=0;e<4;e++){
          int tok = wr*64 + m*16 + ((lane>>4)<<2) + e;
          int col = wc*64 + nf*16 + (lane&15);
          C[(size_t)(row0+tok)*ldc + col0 + col] = acc[m][nf][e];
        }
  } else {
    // stage t-weights bf16 [3][128][32] = 24KB into the (now free) 32KB buffer
    short* t16 = (short*)smem;
    for (int i=tid; i<4096; i+=256){
      t16[i]        = f2bf(tQp[(size_t)row0*32 + i]);
      t16[4096+i]   = f2bf(tKp[(size_t)row0*32 + i]);
      t16[8192+i]   = f2bf(tVp[(size_t)row0*32 + i]);
    }
    __syncthreads();
    int n0 = lane & 15;
    int r_base = (col0 >> 5) + wc*2;
    #pragma unroll
    for (int rec=0; rec<3; rec++){
      const short* tb = t16 + rec*4096;
      short* op = (rec==0) ? Qb : ((rec==1) ? Kb : Vb);
      #pragma unroll
      for (int m=0;m<4;m++){
        #pragma unroll
        for (int g=0; g<2; g++){
          #pragma unroll
          for (int e=0;e<4;e++){
            int tok = wr*64 + m*16 + ((lane>>4)<<2) + e;
            float vv = acc[m][2*g][e]*bf2f(tb[tok*32 + n0]) + acc[m][2*g+1][e]*bf2f(tb[tok*32 + 16 + n0]);
            #pragma unroll
            for (int off=1; off<16; off<<=1) vv += __shfl_xor(vv, off);
            if (n0 == 0) op[(size_t)(row0+tok)*512 + r_base + g] = f2bf(vv);
          }
        }
      }
    }
  }
}

// ---------------- causal flash attention, 1 wave / 16-row q-tile, dh=64 ----------------
__global__ __launch_bounds__(64) void k_attn(const short* __restrict__ Qb, const short* __restrict__ Kb,
                                             const short* __restrict__ Vb, short* __restrict__ Ob)
{
  __shared__ short Ksm[2048];   // [32 kv][64 d]
  __shared__ short Vtsm[2048];  // [64 d][32 kv]
  __shared__ short Psm[512];    // [16 q][32 kv]
  int lane = threadIdx.x;
  int q0 = blockIdx.x << 4, h = blockIdx.y, b = blockIdx.z;
  size_t base = ((size_t)b*2048)*512 + h*64;
  s16x8 qf[2];
  {
    const short* qp = Qb + base + (size_t)(q0 + (lane&15))*512 + ((lane>>4)<<3);
    qf[0] = *(const s16x8*)(qp);
    qf[1] = *(const s16x8*)(qp + 32);
  }
  f32x4 o[4]; float mrow[4], lrow[4], alpha[4];
  #pragma unroll
  for (int i=0;i<4;i++){
    #pragma unroll
    for (int e=0;e<4;e++) o[i][e]=0.f;
    mrow[i]=-INFINITY; lrow[i]=0.f;
  }
  int kv_end = q0 + 16;
  for (int kv0 = 0; kv0 < kv_end; kv0 += 32){
    #pragma unroll
    for (int j=0;j<4;j++){
      int r = (j<<3) + (lane>>3);
      gload16(Kb + base + (size_t)(kv0 + r)*512 + ((lane&7)<<3), (char*)Ksm + j*1024);
      s16x8 vv = *(const s16x8*)(Vb + base + (size_t)(kv0 + r)*512 + ((lane&7)<<3));
      #pragma unroll
      for (int e=0;e<8;e++) Vtsm[(((lane&7)<<3) + e)*32 + r] = vv[e];
    }
    __syncthreads();
    f32x4 S0, S1;
    #pragma unroll
    for (int e=0;e<4;e++){ S0[e]=0.f; S1[e]=0.f; }
    #pragma unroll
    for (int kk=0;kk<2;kk++){
      s16x8 kf0 = *(const s16x8*)(Ksm + ((lane&15))*64 + kk*32 + ((lane>>4)<<3));
      s16x8 kf1 = *(const s16x8*)(Ksm + (16 + (lane&15))*64 + kk*32 + ((lane>>4)<<3));
      S0 = __builtin_amdgcn_mfma_f32_16x16x32_bf16(qf[kk], kf0, S0, 0,0,0);
      S1 = __builtin_amdgcn_mfma_f32_16x16x32_bf16(qf[kk], kf1, S1, 0,0,0);
    }
    #pragma unroll
    for (int e=0;e<4;e++){
      int q = q0 + ((lane>>4)<<2) + e;
      int kvA = kv0 + (lane&15);
      float s0 = S0[e]*0.125f;
      float s1 = S1[e]*0.125f;
      if (kvA > q)      s0 = -1e30f;
      if (kvA + 16 > q) s1 = -1e30f;
      float tm = fmaxf(s0, s1);
      #pragma unroll
      for (int off=1; off<16; off<<=1) tm = fmaxf(tm, __shfl_xor(tm, off));
      float mnew = fmaxf(mrow[e], tm);
      alpha[e] = expf(mrow[e] - mnew);
      float p0 = expf(s0 - mnew), p1 = expf(s1 - mnew);
      float ps = p0 + p1;
      #pragma unroll
      for (int off=1; off<16; off<<=1) ps += __shfl_xor(ps, off);
      lrow[e] = lrow[e]*alpha[e] + ps;
      mrow[e] = mnew;
      int prow = ((lane>>4)<<2) + e;
      Psm[prow*32 + (lane&15)]      = f2bf(p0);
      Psm[prow*32 + 16 + (lane&15)] = f2bf(p1);
    }
    __syncthreads();
    s16x8 pf = *(const s16x8*)(Psm + (lane&15)*32 + ((lane>>4)<<3));
    #pragma unroll
    for (int df=0; df<4; df++){
      s16x8 vf = *(const s16x8*)(Vtsm + (df*16 + (lane&15))*32 + ((lane>>4)<<3));
      f32x4 t;
      #pragma unroll
      for (int e=0;e<4;e++) t[e] = o[df][e]*alpha[e];
      o[df] = __builtin_amdgcn_mfma_f32_16x16x32_bf16(pf, vf, t, 0,0,0);
    }
    __syncthreads();
  }
  #pragma unroll
  for (int df=0; df<4; df++)
    #pragma unroll
    for (int e=0;e<4;e++){
      int q = q0 + ((lane>>4)<<2) + e;
      int d = df*16 + (lane&15);
      Ob[base + (size_t)q*512 + d] = f2bf(o[df][e] / lrow[e]);
    }
}

extern "C" void kernel_launch(void* const* d_in, const int* in_sizes, int n_in,
                              void* d_out, int out_size, void* d_ws, size_t ws_size,
                              hipStream_t stream)
{
  const float* x     = (const float*)d_in[0];
  const float* Wrt   = (const float*)d_in[1];
  const float* rQ    = (const float*)d_in[2];
  const float* rK    = (const float*)d_in[3];
  const float* rV    = (const float*)d_in[4];
  const float* basis = (const float*)d_in[5];
  const float* Wo    = (const float*)d_in[6];
  // d_in[7] = mask (causal tril; reproduced analytically)
  float* out = (float*)d_out;
  char* ws = (char*)d_ws;
  short* B2t = (short*)(ws + 0);          // 32 MB  [16384][1024] bf16
  short* Xb  = (short*)(ws + 33554432);   // 16 MB  [8192][1024]  bf16
  float* SC  = (float*)(ws + 50331648);   // 16 MB  [8192][512]   f32
  float* tQ  = (float*)(ws + 67108864);   // 1 MB
  float* tK  = (float*)(ws + 68157440);   // 1 MB
  float* tV  = (float*)(ws + 69206016);   // 1 MB
  short* Qb  = (short*)(ws + 70254592);   // 8 MB   [8192][512] bf16
  short* Kb  = (short*)(ws + 78643200);   // 8 MB
  short* Vb  = (short*)(ws + 87031808);   // 8 MB
  short* Ob  = (short*)(ws + 95420416);   // 8 MB
  short* Wob = (short*)(ws + 103809024);  // 1 MB   [1024][512] bf16
  float* oidx = out + 8388608;
  float* oww  = out + 8454144;

  k_conv_bf16<<<8192, 256, 0, stream>>>(x, Xb, 2097152);
  k_conv_bf16<<<512, 256, 0, stream>>>(Wo, Wob, 131072);
  k_conv_basis<<<dim3(8,16,32), 256, 0, stream>>>(basis, B2t);
  k_score_gemm<<<dim3(128,8), 256, 0, stream>>>(x, Wrt, SC);
  k_router<<<8192, 64, 0, stream>>>(SC, x, Wrt, rQ, rK, rV, tQ, tK, tV, oidx, oww);
  k_mfma_gemm<1><<<8192, 256, 0, stream>>>(Xb, B2t, 1024, 64, nullptr, 0,
                                           tQ, tK, tV, Qb, Kb, Vb);
  k_attn<<<dim3(128,8,4), 64, 0, stream>>>(Qb, Kb, Vb, Ob);
  k_mfma_gemm<0><<<512, 256, 0, stream>>>(Ob, Wob, 512, 64, out, 1024,
                                          nullptr, nullptr, nullptr, nullptr, nullptr, nullptr);
}

// Round 4
// 969.497 us; speedup vs baseline: 1.4440x; 1.3749x over previous
//
#include <hip/hip_runtime.h>
#include <math.h>
#include <stdint.h>

// Problem constants
// B=4 S=2048 D=1024 N_NEURONS=512 K=8 N_BASIS=32 R=512 H=8 dh=64
// tokens T = 8192

typedef __attribute__((ext_vector_type(4))) float f32x4;
typedef __attribute__((ext_vector_type(8))) short s16x8;
typedef __attribute__((ext_vector_type(4))) short s16x4;

#define DEV __device__ __forceinline__

DEV short f2bf(float f){
  union { float f; unsigned u; } c; c.f = f;
  unsigned u = c.u;
  unsigned r = (u + 0x7fffu + ((u >> 16) & 1u)) >> 16;
  return (short)r;
}
DEV float bf2f(short s){
  union { unsigned u; float f; } c; c.u = ((unsigned)(unsigned short)s) << 16;
  return c.f;
}

typedef __attribute__((address_space(3))) void lds_vt;
typedef const __attribute__((address_space(1))) void g_vt;
DEV void gload16(const void* g, void* lds){
  __builtin_amdgcn_global_load_lds((g_vt*)g, (lds_vt*)lds, 16, 0, 0);
}

// ---------------- elementwise f32 -> bf16 ----------------
__global__ void k_conv_bf16(const float* __restrict__ in, short* __restrict__ out, int n4){
  int i = blockIdx.x*256 + threadIdx.x;
  if (i >= n4) return;
  float4 v = ((const float4*)in)[i];
  s16x4 o; o[0]=f2bf(v.x); o[1]=f2bf(v.y); o[2]=f2bf(v.z); o[3]=f2bf(v.w);
  ((s16x4*)out)[i] = o;
}

// ---------------- basis [32][1024][512] -> B2t bf16 [16384][1024], row c = r*32+n ----------------
__global__ __launch_bounds__(256) void k_conv_basis(const float* __restrict__ basis, short* __restrict__ B2t){
  __shared__ float tile[64][65];
  int tid = threadIdx.x;
  int r0 = blockIdx.x<<6, d0 = blockIdx.y<<6, n = blockIdx.z;
  const float* src = basis + ((size_t)n*1024 + d0)*512 + r0;
  for (int i = tid; i < 4096; i += 256){ int dd = i>>6, rr = i&63; tile[dd][rr] = src[(size_t)dd*512 + rr]; }
  __syncthreads();
  for (int i = tid; i < 4096; i += 256){ int rr = i>>6, dd = i&63;
    B2t[((size_t)(r0+rr)*32 + n)*1024 + d0 + dd] = f2bf(tile[dd][rr]); }
}

// ---------------- bf16 MFMA GEMM 128x128xBK64 -> f32 C (scores, W_o) ----------------
// C = A[M][Kd] @ Bt[N][Kd]^T. 1-D grid, nwg % 8 == 0.
__global__ __launch_bounds__(256) void k_gemm_c32(
    const short* __restrict__ A, const short* __restrict__ Bt, int Kd, int Mblk,
    float* __restrict__ C, int ldc)
{
  __shared__ char smem[32768];
  short* Asm = (short*)smem;
  short* Bsm = (short*)(smem + 16384);
  int tid = threadIdx.x, lane = tid & 63, w = tid >> 6;
  int wr = w >> 1, wc = w & 1;
  int nwg = gridDim.x, bid = blockIdx.x;
  int sid = (bid & 7) * (nwg >> 3) + (bid >> 3);
  int row0 = (sid % Mblk) << 7;
  int col0 = (sid / Mblk) << 7;
  f32x4 acc[4][4];
  #pragma unroll
  for (int m=0;m<4;m++)
    #pragma unroll
    for (int nf=0;nf<4;nf++)
      #pragma unroll
      for (int e=0;e<4;e++) acc[m][nf][e] = 0.f;
  int lr8 = lane >> 3;
  int lk_sw = (((lane & 7) ^ (lane >> 3)) << 3);
  for (int k0 = 0; k0 < Kd; k0 += 64){
    #pragma unroll
    for (int i=0;i<4;i++){
      int chunk = (w<<2) + i;
      int r = (chunk<<3) + lr8;
      gload16(A  + (size_t)(row0 + r)*Kd + k0 + lk_sw, smem + chunk*1024);
      gload16(Bt + (size_t)(col0 + r)*Kd + k0 + lk_sw, smem + 16384 + chunk*1024);
    }
    __syncthreads();
    #pragma unroll
    for (int kk=0; kk<2; kk++){
      int csw = (kk*32 + ((lane>>4)<<3)) ^ ((lane & 7) << 3);
      s16x8 af[4], bfr[4];
      #pragma unroll
      for (int m=0;m<4;m++)
        af[m] = *(const s16x8*)(Asm + ((wr*64 + m*16 + (lane&15))*64 + csw));
      #pragma unroll
      for (int nf=0;nf<4;nf++)
        bfr[nf] = *(const s16x8*)(Bsm + ((wc*64 + nf*16 + (lane&15))*64 + csw));
      #pragma unroll
      for (int m=0;m<4;m++)
        #pragma unroll
        for (int nf=0;nf<4;nf++)
          acc[m][nf] = __builtin_amdgcn_mfma_f32_16x16x32_bf16(af[m], bfr[nf], acc[m][nf], 0, 0, 0);
    }
    __syncthreads();
  }
  #pragma unroll
  for (int m=0;m<4;m++)
    #pragma unroll
    for (int nf=0;nf<4;nf++)
      #pragma unroll
      for (int e=0;e<4;e++){
        int tok = wr*64 + m*16 + ((lane>>4)<<2) + e;
        int col = wc*64 + nf*16 + (lane&15);
        C[(size_t)(row0+tok)*ldc + col0 + col] = acc[m][nf][e];
      }
}

// ---------------- fused P-GEMM, TRANSPOSED: C[c = r*32+n][tok], in-lane n-contraction ----------------
// A-operand = B2t rows (basis cols), B-operand = Xb rows (tokens).
__global__ __launch_bounds__(256) void k_pgemm(
    const short* __restrict__ B2t, const short* __restrict__ Xb,
    const float* __restrict__ tQp, const float* __restrict__ tKp, const float* __restrict__ tVp,
    short* __restrict__ Qb, short* __restrict__ Kb, short* __restrict__ Vb)
{
  __shared__ char smem[32768];
  short* Asm = (short*)smem;            // B2t tile [128 c][64 d], T2-swizzled
  short* Bsm = (short*)(smem + 16384);  // Xb tile [128 tok][64 d], T2-swizzled
  int tid = threadIdx.x, lane = tid & 63, w = tid >> 6;
  int wr = w >> 1, wc = w & 1;
  // XCD chunking: xcd owns 16 c-blocks (A chunk 4MB, L2-resident); 8x8 supertiles inside.
  int bid = blockIdx.x;
  int xcd = bid & 7, lid = bid >> 3;            // lid < 1024
  int c_blk = xcd*16 + ((lid>>9)<<3) + (lid&7); // 0..127
  int t_blk = (lid>>3) & 63;                    // 0..63
  int row0 = c_blk << 7;   // basis-col base
  int col0 = t_blk << 7;   // token base
  f32x4 acc[4][4];
  #pragma unroll
  for (int m=0;m<4;m++)
    #pragma unroll
    for (int nf=0;nf<4;nf++)
      #pragma unroll
      for (int e=0;e<4;e++) acc[m][nf][e] = 0.f;
  int lr8 = lane >> 3;
  int lk_sw = (((lane & 7) ^ (lane >> 3)) << 3);
  for (int k0 = 0; k0 < 1024; k0 += 64){
    #pragma unroll
    for (int i=0;i<4;i++){
      int chunk = (w<<2) + i;
      int r = (chunk<<3) + lr8;
      gload16(B2t + (size_t)(row0 + r)*1024 + k0 + lk_sw, smem + chunk*1024);
      gload16(Xb  + (size_t)(col0 + r)*1024 + k0 + lk_sw, smem + 16384 + chunk*1024);
    }
    __syncthreads();
    #pragma unroll
    for (int kk=0; kk<2; kk++){
      int csw = (kk*32 + ((lane>>4)<<3)) ^ ((lane & 7) << 3);
      s16x8 af[4], bfr[4];
      #pragma unroll
      for (int m=0;m<4;m++)
        af[m] = *(const s16x8*)(Asm + ((wr*64 + m*16 + (lane&15))*64 + csw));
      #pragma unroll
      for (int nf=0;nf<4;nf++)
        bfr[nf] = *(const s16x8*)(Bsm + ((wc*64 + nf*16 + (lane&15))*64 + csw));
      #pragma unroll
      for (int m=0;m<4;m++)
        #pragma unroll
        for (int nf=0;nf<4;nf++)
          acc[m][nf] = __builtin_amdgcn_mfma_f32_16x16x32_bf16(af[m], bfr[nf], acc[m][nf], 0, 0, 0);
    }
    __syncthreads();
  }
  // ---- epilogue: Q/K/V[tok][r] = sum_n C[r*32+n][tok] * t[tok][n] ----
  // C row (in-wave): c = wr*64 + m*16 + (lane>>4)*4 + e  ->  n = (m&1)*16 + (lane>>4)*4 + e, r_loc = m>>1
  // C col: tok = wc*64 + nf*16 + (lane&15)
  short* t16 = (short*)smem;   // [128 tok][stride 36] bf16, 3 recs = 27.6KB
  for (int i = tid; i < 4096; i += 256){
    int tk = i >> 5, n = i & 31;
    t16[tk*36 + n]           = f2bf(tQp[(size_t)col0*32 + i]);
    t16[4608 + tk*36 + n]    = f2bf(tKp[(size_t)col0*32 + i]);
    t16[9216 + tk*36 + n]    = f2bf(tVp[(size_t)col0*32 + i]);
  }
  __syncthreads();
  int g4 = (lane>>4)<<2, tokl = lane & 15;
  int rbase = (row0 + wr*64) >> 5;   // global r of m-pair 0
  #pragma unroll
  for (int rec=0; rec<3; rec++){
    const short* tb = t16 + rec*4608;
    short* op = (rec==0) ? Qb : ((rec==1) ? Kb : Vb);
    #pragma unroll
    for (int nf=0;nf<4;nf++){
      int tok = wc*64 + nf*16 + tokl;            // local token 0..127
      s16x4 tlo = *(const s16x4*)(tb + tok*36 + g4);
      s16x4 thi = *(const s16x4*)(tb + tok*36 + 16 + g4);
      #pragma unroll
      for (int r=0;r<2;r++){
        float p = 0.f;
        #pragma unroll
        for (int e=0;e<4;e++) p += acc[2*r][nf][e]   * bf2f(tlo[e]);   // n = g4+e
        #pragma unroll
        for (int e=0;e<4;e++) p += acc[2*r+1][nf][e] * bf2f(thi[e]);   // n = 16+g4+e
        p += __shfl_xor(p, 16);
        p += __shfl_xor(p, 32);
        if ((lane>>4) == rec)
          op[(size_t)(col0 + tok)*512 + rbase + r] = f2bf(p);
      }
    }
  }
}

// ---------------- router: bf16-MFMA scores -> top-32 candidates -> f64 exact rescore -> top-8 ----------------
__global__ __launch_bounds__(64) void k_router(const float* __restrict__ scores,
    const float* __restrict__ X, const float* __restrict__ W,
    const float* __restrict__ rQ, const float* __restrict__ rK, const float* __restrict__ rV,
    float* __restrict__ tQ, float* __restrict__ tK, float* __restrict__ tV,
    float* __restrict__ oidx, float* __restrict__ ow){
  int token = blockIdx.x; int lane = threadIdx.x;
  const float* srow = scores + (size_t)token*512;
  float v[8];
  #pragma unroll
  for (int j=0;j<8;j++) v[j] = srow[lane + 64*j];
  // ---- stage 1: top-32 candidates by approx score (margin >> bf16 error) ----
  int myidx = 0x7fffffff;
  #pragma unroll
  for (int k=0;k<32;k++){
    float bm = -INFINITY; int bi = 0x7fffffff;
    #pragma unroll
    for (int j=0;j<8;j++){ if (v[j] > bm) { bm = v[j]; bi = lane + 64*j; } }
    #pragma unroll
    for (int off=32; off>=1; off>>=1){
      float om = __shfl_xor(bm, off); int oi = __shfl_xor(bi, off);
      if (om > bm || (om == bm && oi < bi)) { bm = om; bi = oi; }
    }
    if (lane == k) myidx = bi;
    #pragma unroll
    for (int j=0;j<8;j++) if (lane + 64*j == bi) v[j] = -INFINITY;
  }
  // ---- stage 2: exact f64 rescore of the 32 candidates ----
  float xr[16];
  {
    const float4* x4 = (const float4*)(X + (size_t)token*1024 + lane*16);
    #pragma unroll
    for (int q=0;q<4;q++){ float4 t = x4[q]; xr[q*4]=t.x; xr[q*4+1]=t.y; xr[q*4+2]=t.z; xr[q*4+3]=t.w; }
  }
  double myref = -1e300;
  #pragma unroll
  for (int c=0;c<32;c++){
    int nid = __shfl(myidx, c);
    const float4* w4 = (const float4*)(W + (size_t)nid*1024 + lane*16);
    double acc = 0.0;
    #pragma unroll
    for (int q=0;q<4;q++){
      float4 t = w4[q];
      acc += (double)xr[q*4]   * (double)t.x;
      acc += (double)xr[q*4+1] * (double)t.y;
      acc += (double)xr[q*4+2] * (double)t.z;
      acc += (double)xr[q*4+3] * (double)t.w;
    }
    #pragma unroll
    for (int off=32; off>=1; off>>=1) acc += __shfl_xor(acc, off);
    if (lane == c) myref = acc;
  }
  // ---- stage 3: top-8 over the f64-refined scores ----
  double mv = myref; int mi = myidx;
  double topv[8]; int topi[8];
  #pragma unroll
  for (int k=0;k<8;k++){
    double bm = mv; int bi = mi;
    #pragma unroll
    for (int off=32; off>=1; off>>=1){
      double om = __shfl_xor(bm, off); int oi = __shfl_xor(bi, off);
      if (om > bm || (om == bm && oi < bi)) { bm = om; bi = oi; }
    }
    topv[k]=bm; topi[k]=bi;
    if (mi == bi) mv = -1e300;
  }
  double mx = topv[0]; double s = 0.0; double wd[8];
  #pragma unroll
  for (int k=0;k<8;k++){ wd[k] = exp(topv[k]-mx); s += wd[k]; }
  float w[8];
  #pragma unroll
  for (int k=0;k<8;k++) w[k] = (float)(wd[k]/s);
  if (lane == 0){
    #pragma unroll
    for (int k=0;k<8;k++){ oidx[(size_t)token*8+k] = (float)topi[k]; ow[(size_t)token*8+k] = w[k]; }
  }
  // ---- recipe softmaxes ----
  int n = lane & 31;
  float aq=0.f, ak=0.f, av=0.f;
  #pragma unroll
  for (int k=0;k<8;k++){
    size_t off = (size_t)topi[k]*32 + n;
    aq += w[k]*rQ[off]; ak += w[k]*rK[off]; av += w[k]*rV[off];
  }
  float mq = aq, mk2 = ak, mvv = av;
  #pragma unroll
  for (int off=16; off>=1; off>>=1){
    mq  = fmaxf(mq,  __shfl_xor(mq, off));
    mk2 = fmaxf(mk2, __shfl_xor(mk2,off));
    mvv = fmaxf(mvv, __shfl_xor(mvv,off));
  }
  float eq = expf(aq-mq), ek = expf(ak-mk2), ev = expf(av-mvv);
  float sq = eq, sk = ek, sv = ev;
  #pragma unroll
  for (int off=16; off>=1; off>>=1){
    sq += __shfl_xor(sq,off); sk += __shfl_xor(sk,off); sv += __shfl_xor(sv,off);
  }
  if (lane < 32){
    tQ[(size_t)token*32+n] = eq/sq;
    tK[(size_t)token*32+n] = ek/sk;
    tV[(size_t)token*32+n] = ev/sv;
  }
}

// ---------------- causal flash attention, 1 wave / 16-row q-tile, dh=64 ----------------
__global__ __launch_bounds__(64) void k_attn(const short* __restrict__ Qb, const short* __restrict__ Kb,
                                             const short* __restrict__ Vb, short* __restrict__ Ob)
{
  __shared__ short Ksm[2048];   // [32 kv][64 d]
  __shared__ short Vtsm[2048];  // [64 d][32 kv]
  __shared__ short Psm[512];    // [16 q][32 kv]
  int lane = threadIdx.x;
  int q0 = blockIdx.x << 4, h = blockIdx.y, b = blockIdx.z;
  size_t base = ((size_t)b*2048)*512 + h*64;
  s16x8 qf[2];
  {
    const short* qp = Qb + base + (size_t)(q0 + (lane&15))*512 + ((lane>>4)<<3);
    qf[0] = *(const s16x8*)(qp);
    qf[1] = *(const s16x8*)(qp + 32);
  }
  f32x4 o[4]; float mrow[4], lrow[4], alpha[4];
  #pragma unroll
  for (int i=0;i<4;i++){
    #pragma unroll
    for (int e=0;e<4;e++) o[i][e]=0.f;
    mrow[i]=-INFINITY; lrow[i]=0.f;
  }
  int kv_end = q0 + 16;
  for (int kv0 = 0; kv0 < kv_end; kv0 += 32){
    #pragma unroll
    for (int j=0;j<4;j++){
      int r = (j<<3) + (lane>>3);
      gload16(Kb + base + (size_t)(kv0 + r)*512 + ((lane&7)<<3), (char*)Ksm + j*1024);
      s16x8 vv = *(const s16x8*)(Vb + base + (size_t)(kv0 + r)*512 + ((lane&7)<<3));
      #pragma unroll
      for (int e=0;e<8;e++) Vtsm[(((lane&7)<<3) + e)*32 + r] = vv[e];
    }
    __syncthreads();
    f32x4 S0, S1;
    #pragma unroll
    for (int e=0;e<4;e++){ S0[e]=0.f; S1[e]=0.f; }
    #pragma unroll
    for (int kk=0;kk<2;kk++){
      s16x8 kf0 = *(const s16x8*)(Ksm + ((lane&15))*64 + kk*32 + ((lane>>4)<<3));
      s16x8 kf1 = *(const s16x8*)(Ksm + (16 + (lane&15))*64 + kk*32 + ((lane>>4)<<3));
      S0 = __builtin_amdgcn_mfma_f32_16x16x32_bf16(qf[kk], kf0, S0, 0,0,0);
      S1 = __builtin_amdgcn_mfma_f32_16x16x32_bf16(qf[kk], kf1, S1, 0,0,0);
    }
    #pragma unroll
    for (int e=0;e<4;e++){
      int q = q0 + ((lane>>4)<<2) + e;
      int kvA = kv0 + (lane&15);
      float s0 = S0[e]*0.125f;
      float s1 = S1[e]*0.125f;
      if (kvA > q)      s0 = -1e30f;
      if (kvA + 16 > q) s1 = -1e30f;
      float tm = fmaxf(s0, s1);
      #pragma unroll
      for (int off=1; off<16; off<<=1) tm = fmaxf(tm, __shfl_xor(tm, off));
      float mnew = fmaxf(mrow[e], tm);
      alpha[e] = expf(mrow[e] - mnew);
      float p0 = expf(s0 - mnew), p1 = expf(s1 - mnew);
      float ps = p0 + p1;
      #pragma unroll
      for (int off=1; off<16; off<<=1) ps += __shfl_xor(ps, off);
      lrow[e] = lrow[e]*alpha[e] + ps;
      mrow[e] = mnew;
      int prow = ((lane>>4)<<2) + e;
      Psm[prow*32 + (lane&15)]      = f2bf(p0);
      Psm[prow*32 + 16 + (lane&15)] = f2bf(p1);
    }
    __syncthreads();
    s16x8 pf = *(const s16x8*)(Psm + (lane&15)*32 + ((lane>>4)<<3));
    #pragma unroll
    for (int df=0; df<4; df++){
      s16x8 vf = *(const s16x8*)(Vtsm + (df*16 + (lane&15))*32 + ((lane>>4)<<3));
      f32x4 t;
      #pragma unroll
      for (int e=0;e<4;e++) t[e] = o[df][e]*alpha[e];
      o[df] = __builtin_amdgcn_mfma_f32_16x16x32_bf16(pf, vf, t, 0,0,0);
    }
    __syncthreads();
  }
  #pragma unroll
  for (int df=0; df<4; df++)
    #pragma unroll
    for (int e=0;e<4;e++){
      int q = q0 + ((lane>>4)<<2) + e;
      int d = df*16 + (lane&15);
      Ob[base + (size_t)q*512 + d] = f2bf(o[df][e] / lrow[e]);
    }
}

extern "C" void kernel_launch(void* const* d_in, const int* in_sizes, int n_in,
                              void* d_out, int out_size, void* d_ws, size_t ws_size,
                              hipStream_t stream)
{
  const float* x     = (const float*)d_in[0];
  const float* Wrt   = (const float*)d_in[1];
  const float* rQ    = (const float*)d_in[2];
  const float* rK    = (const float*)d_in[3];
  const float* rV    = (const float*)d_in[4];
  const float* basis = (const float*)d_in[5];
  const float* Wo    = (const float*)d_in[6];
  // d_in[7] = mask (causal tril; reproduced analytically)
  float* out = (float*)d_out;
  char* ws = (char*)d_ws;
  short* B2t  = (short*)(ws + 0);          // 32 MB  [16384][1024] bf16
  short* Xb   = (short*)(ws + 33554432);   // 16 MB  [8192][1024]  bf16
  float* SC   = (float*)(ws + 50331648);   // 16 MB  [8192][512]   f32
  float* tQ   = (float*)(ws + 67108864);   // 1 MB
  float* tK   = (float*)(ws + 68157440);   // 1 MB
  float* tV   = (float*)(ws + 69206016);   // 1 MB
  short* Qb   = (short*)(ws + 70254592);   // 8 MB   [8192][512] bf16
  short* Kb   = (short*)(ws + 78643200);   // 8 MB
  short* Vb   = (short*)(ws + 87031808);   // 8 MB
  short* Ob   = (short*)(ws + 95420416);   // 8 MB
  short* Wob  = (short*)(ws + 103809024);  // 1 MB   [1024][512] bf16
  short* Wrtb = (short*)(ws + 104857600);  // 1 MB   [512][1024] bf16
  float* oidx = out + 8388608;
  float* oww  = out + 8454144;

  k_conv_bf16<<<8192, 256, 0, stream>>>(x, Xb, 2097152);
  k_conv_bf16<<<512, 256, 0, stream>>>(Wo, Wob, 131072);
  k_conv_bf16<<<512, 256, 0, stream>>>(Wrt, Wrtb, 131072);
  k_conv_basis<<<dim3(8,16,32), 256, 0, stream>>>(basis, B2t);
  // scores: SC[8192][512] = Xb @ Wrtb^T (approx, bf16)
  k_gemm_c32<<<256, 256, 0, stream>>>(Xb, Wrtb, 1024, 64, SC, 512);
  k_router<<<8192, 64, 0, stream>>>(SC, x, Wrt, rQ, rK, rV, tQ, tK, tV, oidx, oww);
  k_pgemm<<<8192, 256, 0, stream>>>(B2t, Xb, tQ, tK, tV, Qb, Kb, Vb);
  k_attn<<<dim3(128,8,4), 64, 0, stream>>>(Qb, Kb, Vb, Ob);
  // out[8192][1024] = Ob @ Wob^T
  k_gemm_c32<<<512, 256, 0, stream>>>(Ob, Wob, 512, 64, out, 1024);
}

// Round 5
// 860.612 us; speedup vs baseline: 1.6267x; 1.1265x over previous
//
#include <hip/hip_runtime.h>
#include <math.h>
#include <stdint.h>

// Problem constants
// B=4 S=2048 D=1024 N_NEURONS=512 K=8 N_BASIS=32 R=512 H=8 dh=64
// tokens T = 8192

typedef __attribute__((ext_vector_type(4))) float f32x4;
typedef __attribute__((ext_vector_type(8))) short s16x8;
typedef __attribute__((ext_vector_type(4))) short s16x4;

#define DEV __device__ __forceinline__

DEV short f2bf(float f){
  union { float f; unsigned u; } c; c.f = f;
  unsigned u = c.u;
  unsigned r = (u + 0x7fffu + ((u >> 16) & 1u)) >> 16;
  return (short)r;
}
DEV float bf2f(short s){
  union { unsigned u; float f; } c; c.u = ((unsigned)(unsigned short)s) << 16;
  return c.f;
}

typedef __attribute__((address_space(3))) void lds_vt;
typedef const __attribute__((address_space(1))) void g_vt;
DEV void gload16(const void* g, void* lds){
  __builtin_amdgcn_global_load_lds((g_vt*)g, (lds_vt*)lds, 16, 0, 0);
}

DEV void hard_barrier(){
  __builtin_amdgcn_sched_barrier(0);
  __builtin_amdgcn_s_barrier();
  __builtin_amdgcn_sched_barrier(0);
}

// ---------------- elementwise f32 -> bf16 ----------------
__global__ void k_conv_bf16(const float* __restrict__ in, short* __restrict__ out, int n4){
  int i = blockIdx.x*256 + threadIdx.x;
  if (i >= n4) return;
  float4 v = ((const float4*)in)[i];
  s16x4 o; o[0]=f2bf(v.x); o[1]=f2bf(v.y); o[2]=f2bf(v.z); o[3]=f2bf(v.w);
  ((s16x4*)out)[i] = o;
}

// ---------------- basis [32][1024][512] -> B2t bf16 [16384][1024], row c = r*32+n ----------------
__global__ __launch_bounds__(256) void k_conv_basis(const float* __restrict__ basis, short* __restrict__ B2t){
  __shared__ float tile[64][65];
  int tid = threadIdx.x;
  int r0 = blockIdx.x<<6, d0 = blockIdx.y<<6, n = blockIdx.z;
  const float* src = basis + ((size_t)n*1024 + d0)*512 + r0;
  for (int i = tid; i < 4096; i += 256){ int dd = i>>6, rr = i&63; tile[dd][rr] = src[(size_t)dd*512 + rr]; }
  __syncthreads();
  for (int i = tid; i < 4096; i += 256){ int rr = i>>6, dd = i&63;
    B2t[((size_t)(r0+rr)*32 + n)*1024 + d0 + dd] = f2bf(tile[dd][rr]); }
}

// ---------------- bf16 MFMA GEMM 128x128xBK64 -> f32 C (scores, W_o) ----------------
__global__ __launch_bounds__(256) void k_gemm_c32(
    const short* __restrict__ A, const short* __restrict__ Bt, int Kd, int Mblk,
    float* __restrict__ C, int ldc)
{
  __shared__ char smem[32768];
  short* Asm = (short*)smem;
  short* Bsm = (short*)(smem + 16384);
  int tid = threadIdx.x, lane = tid & 63, w = tid >> 6;
  int wr = w >> 1, wc = w & 1;
  int nwg = gridDim.x, bid = blockIdx.x;
  int sid = (bid & 7) * (nwg >> 3) + (bid >> 3);
  int row0 = (sid % Mblk) << 7;
  int col0 = (sid / Mblk) << 7;
  f32x4 acc[4][4];
  #pragma unroll
  for (int m=0;m<4;m++)
    #pragma unroll
    for (int nf=0;nf<4;nf++)
      #pragma unroll
      for (int e=0;e<4;e++) acc[m][nf][e] = 0.f;
  int lr8 = lane >> 3;
  int lk_sw = (((lane & 7) ^ (lane >> 3)) << 3);
  for (int k0 = 0; k0 < Kd; k0 += 64){
    #pragma unroll
    for (int i=0;i<4;i++){
      int chunk = (w<<2) + i;
      int r = (chunk<<3) + lr8;
      gload16(A  + (size_t)(row0 + r)*Kd + k0 + lk_sw, smem + chunk*1024);
      gload16(Bt + (size_t)(col0 + r)*Kd + k0 + lk_sw, smem + 16384 + chunk*1024);
    }
    __syncthreads();
    #pragma unroll
    for (int kk=0; kk<2; kk++){
      int csw = (kk*32 + ((lane>>4)<<3)) ^ ((lane & 7) << 3);
      s16x8 af[4], bfr[4];
      #pragma unroll
      for (int m=0;m<4;m++)
        af[m] = *(const s16x8*)(Asm + ((wr*64 + m*16 + (lane&15))*64 + csw));
      #pragma unroll
      for (int nf=0;nf<4;nf++)
        bfr[nf] = *(const s16x8*)(Bsm + ((wc*64 + nf*16 + (lane&15))*64 + csw));
      #pragma unroll
      for (int m=0;m<4;m++)
        #pragma unroll
        for (int nf=0;nf<4;nf++)
          acc[m][nf] = __builtin_amdgcn_mfma_f32_16x16x32_bf16(af[m], bfr[nf], acc[m][nf], 0, 0, 0);
    }
    __syncthreads();
  }
  #pragma unroll
  for (int m=0;m<4;m++)
    #pragma unroll
    for (int nf=0;nf<4;nf++)
      #pragma unroll
      for (int e=0;e<4;e++){
        int tok = wr*64 + m*16 + ((lane>>4)<<2) + e;
        int col = wc*64 + nf*16 + (lane&15);
        C[(size_t)(row0+tok)*ldc + col0 + col] = acc[m][nf][e];
      }
}

// ---------------- fused P-GEMM, 256x256 8-phase deep pipeline ----------------
// C[c = r*32+n][tok] = B2t[16384][1024] @ Xb[8192][1024]^T, fused n-contract -> Q/K/V bf16.
// 512 thr = 8 waves (2M x 4N); LDS 128 KiB: A[2buf][2half][128][64]bf16, B same at +65536.
// Stage slots per K-tile kt: p0:A-h1(kt+1) p1:B-h0(kt+1) p2:B-h1(kt+1) p3:A-h0(kt+2);
// vmcnt(2) once per K-tile (leaves newest half-tile in flight).
#define STAGE(G, tileRow0, half, tkt, bufOff) do{ \
  char* _d = smem + (bufOff) + (((tkt)&1)*32768) + ((half)*16384) + (wid*2048); \
  const short* _s = (G) + (size_t)((tileRow0) + (half)*128 + wid*16 + (lane>>3))*1024 + ((tkt)<<6) + (((lane&7)^(lane>>3))<<3); \
  gload16(_s, _d); \
  gload16(_s + 8192, _d + 1024); \
}while(0)

#define LDA(MOFF) \
  _Pragma("unroll") \
  for (int i=0;i<4;i++){ \
    const char* _p = Acur + ((MOFF) + i*16 + l15)*128; \
    _Pragma("unroll") \
    for (int kk=0;kk<2;kk++) \
      af[i][kk] = *(const s16x8*)(_p + ((((kk<<2)+g16) ^ l7)<<4)); \
  }

#define LDB(N0) \
  _Pragma("unroll") \
  for (int n=0;n<2;n++){ \
    const char* _p = Bcur + (((wc&1)*64) + ((N0)+n)*16 + l15)*128; \
    _Pragma("unroll") \
    for (int kk=0;kk<2;kk++) \
      bf_[(N0)+n][kk] = *(const s16x8*)(_p + ((((kk<<2)+g16) ^ l7)<<4)); \
  }

#define LGKM0() do{ \
  asm volatile("s_waitcnt lgkmcnt(0)" ::: "memory"); \
  __builtin_amdgcn_sched_barrier(0); \
}while(0)

#define MFMA_QUAD(MB, NB) do{ \
  __builtin_amdgcn_s_setprio(1); \
  _Pragma("unroll") \
  for (int kk=0;kk<2;kk++) \
    _Pragma("unroll") \
    for (int i=0;i<4;i++) \
      _Pragma("unroll") \
      for (int n=0;n<2;n++) \
        acc[(MB)+i][(NB)+n] = __builtin_amdgcn_mfma_f32_16x16x32_bf16(af[i][kk], bf_[(NB)+n][kk], acc[(MB)+i][(NB)+n], 0,0,0); \
  __builtin_amdgcn_s_setprio(0); \
}while(0)

__global__ __launch_bounds__(512, 2) void k_pgemm8(
    const short* __restrict__ B2t, const short* __restrict__ Xb,
    const float* __restrict__ tQp, const float* __restrict__ tKp, const float* __restrict__ tVp,
    short* __restrict__ Qb, short* __restrict__ Kb, short* __restrict__ Vb)
{
  extern __shared__ char smem[];
  int tid = threadIdx.x, lane = tid & 63, wid = tid >> 6;
  int wr = wid >> 2, wc = wid & 3;
  int l15 = lane & 15, l7 = lane & 7, g16 = lane >> 4;
  // XCD map: each XCD owns 4 token-tiles (B-chunk 2MB, L2-resident); c streams.
  int bid = blockIdx.x;
  int xcd = bid & 7, lid = bid >> 3;        // lid 0..255
  int t_tile = (xcd << 2) + (lid & 3);      // 0..31
  int c_tile = lid >> 2;                    // 0..63
  int row0 = c_tile << 8;                   // B2t row base
  int col0 = t_tile << 8;                   // token base

  f32x4 acc[8][4];
  #pragma unroll
  for (int m=0;m<8;m++)
    #pragma unroll
    for (int n=0;n<4;n++)
      #pragma unroll
      for (int e=0;e<4;e++) acc[m][n][e] = 0.f;
  s16x8 af[4][2], bf_[4][2];

  // prologue: kt0 full + A-h0(1); vmcnt(2) leaves A-h0(1) in flight
  STAGE(B2t, row0, 0, 0, 0);
  STAGE(B2t, row0, 1, 0, 0);
  STAGE(Xb,  col0, 0, 0, 65536);
  STAGE(Xb,  col0, 1, 0, 65536);
  STAGE(B2t, row0, 0, 1, 0);
  asm volatile("s_waitcnt vmcnt(2)" ::: "memory");
  hard_barrier();

  for (int kt = 0; kt < 16; ++kt){
    const int cur = kt & 1;
    const char* Acur = smem + cur*32768 + wr*16384;
    const char* Bcur = smem + 65536 + cur*32768 + ((wc>>1)*16384);
    // ---- phase 0 ----
    LDA(0); LDB(0);
    if (kt < 15) STAGE(B2t, row0, 1, kt+1, 0);
    hard_barrier();
    LGKM0();
    MFMA_QUAD(0, 0);
    hard_barrier();
    // ---- phase 1 ----
    LDB(2);
    if (kt < 15) STAGE(Xb, col0, 0, kt+1, 65536);
    hard_barrier();
    LGKM0();
    MFMA_QUAD(0, 2);
    hard_barrier();
    // ---- phase 2 ----
    LDA(64);
    if (kt < 15) STAGE(Xb, col0, 1, kt+1, 65536);
    hard_barrier();
    LGKM0();
    MFMA_QUAD(4, 0);
    hard_barrier();
    // ---- phase 3 ----
    if (kt < 14) STAGE(B2t, row0, 0, kt+2, 0);
    MFMA_QUAD(4, 2);
    asm volatile("s_waitcnt vmcnt(2)" ::: "memory");
    hard_barrier();
  }

  // ---- fused epilogue: Q/K/V[tok][r] = sum_n C[r*32+n][tok] * t[tok][n] ----
  // c = row0 + wr*128 + m*16 + g16*4 + e -> n = (m&1)*16 + g16*4 + e, r = row0/32 + wr*4 + (m>>1)
  __syncthreads();
  short* t16 = (short*)smem;    // [3][256 tok][36] bf16 = 55296 B
  for (int i = tid; i < 8192; i += 512){
    int tk = i >> 5, n = i & 31;
    t16[tk*36 + n]            = f2bf(tQp[(size_t)col0*32 + i]);
    t16[9216 + tk*36 + n]     = f2bf(tKp[(size_t)col0*32 + i]);
    t16[18432 + tk*36 + n]    = f2bf(tVp[(size_t)col0*32 + i]);
  }
  __syncthreads();
  int g4 = g16 << 2, tokl = l15;
  int rb = (row0 >> 5) + (wr << 2);
  #pragma unroll
  for (int rec=0; rec<3; rec++){
    const short* tb = t16 + rec*9216;
    short* op = (rec==0) ? Qb : ((rec==1) ? Kb : Vb);
    #pragma unroll
    for (int nf=0;nf<4;nf++){
      int tok = wc*64 + nf*16 + tokl;
      s16x4 tlo = *(const s16x4*)(tb + tok*36 + g4);
      s16x4 thi = *(const s16x4*)(tb + tok*36 + 16 + g4);
      #pragma unroll
      for (int mp=0;mp<4;mp++){
        float p = 0.f;
        #pragma unroll
        for (int e=0;e<4;e++) p += acc[2*mp][nf][e]   * bf2f(tlo[e]);
        #pragma unroll
        for (int e=0;e<4;e++) p += acc[2*mp+1][nf][e] * bf2f(thi[e]);
        p += __shfl_xor(p, 16);
        p += __shfl_xor(p, 32);
        if (g16 == rec)
          op[(size_t)(col0 + tok)*512 + rb + mp] = f2bf(p);
      }
    }
  }
}

// ---------------- router: bf16-MFMA scores -> top-32 candidates -> f64 exact rescore -> top-8 ----------------
__global__ __launch_bounds__(64) void k_router(const float* __restrict__ scores,
    const float* __restrict__ X, const float* __restrict__ W,
    const float* __restrict__ rQ, const float* __restrict__ rK, const float* __restrict__ rV,
    float* __restrict__ tQ, float* __restrict__ tK, float* __restrict__ tV,
    float* __restrict__ oidx, float* __restrict__ ow){
  int token = blockIdx.x; int lane = threadIdx.x;
  const float* srow = scores + (size_t)token*512;
  float v[8];
  #pragma unroll
  for (int j=0;j<8;j++) v[j] = srow[lane + 64*j];
  int myidx = 0x7fffffff;
  #pragma unroll
  for (int k=0;k<32;k++){
    float bm = -INFINITY; int bi = 0x7fffffff;
    #pragma unroll
    for (int j=0;j<8;j++){ if (v[j] > bm) { bm = v[j]; bi = lane + 64*j; } }
    #pragma unroll
    for (int off=32; off>=1; off>>=1){
      float om = __shfl_xor(bm, off); int oi = __shfl_xor(bi, off);
      if (om > bm || (om == bm && oi < bi)) { bm = om; bi = oi; }
    }
    if (lane == k) myidx = bi;
    #pragma unroll
    for (int j=0;j<8;j++) if (lane + 64*j == bi) v[j] = -INFINITY;
  }
  float xr[16];
  {
    const float4* x4 = (const float4*)(X + (size_t)token*1024 + lane*16);
    #pragma unroll
    for (int q=0;q<4;q++){ float4 t = x4[q]; xr[q*4]=t.x; xr[q*4+1]=t.y; xr[q*4+2]=t.z; xr[q*4+3]=t.w; }
  }
  double myref = -1e300;
  #pragma unroll
  for (int c=0;c<32;c++){
    int nid = __shfl(myidx, c);
    const float4* w4 = (const float4*)(W + (size_t)nid*1024 + lane*16);
    double acc = 0.0;
    #pragma unroll
    for (int q=0;q<4;q++){
      float4 t = w4[q];
      acc += (double)xr[q*4]   * (double)t.x;
      acc += (double)xr[q*4+1] * (double)t.y;
      acc += (double)xr[q*4+2] * (double)t.z;
      acc += (double)xr[q*4+3] * (double)t.w;
    }
    #pragma unroll
    for (int off=32; off>=1; off>>=1) acc += __shfl_xor(acc, off);
    if (lane == c) myref = acc;
  }
  double mv = myref; int mi = myidx;
  double topv[8]; int topi[8];
  #pragma unroll
  for (int k=0;k<8;k++){
    double bm = mv; int bi = mi;
    #pragma unroll
    for (int off=32; off>=1; off>>=1){
      double om = __shfl_xor(bm, off); int oi = __shfl_xor(bi, off);
      if (om > bm || (om == bm && oi < bi)) { bm = om; bi = oi; }
    }
    topv[k]=bm; topi[k]=bi;
    if (mi == bi) mv = -1e300;
  }
  double mx = topv[0]; double s = 0.0; double wd[8];
  #pragma unroll
  for (int k=0;k<8;k++){ wd[k] = exp(topv[k]-mx); s += wd[k]; }
  float w[8];
  #pragma unroll
  for (int k=0;k<8;k++) w[k] = (float)(wd[k]/s);
  if (lane == 0){
    #pragma unroll
    for (int k=0;k<8;k++){ oidx[(size_t)token*8+k] = (float)topi[k]; ow[(size_t)token*8+k] = w[k]; }
  }
  int n = lane & 31;
  float aq=0.f, ak=0.f, av=0.f;
  #pragma unroll
  for (int k=0;k<8;k++){
    size_t off = (size_t)topi[k]*32 + n;
    aq += w[k]*rQ[off]; ak += w[k]*rK[off]; av += w[k]*rV[off];
  }
  float mq = aq, mk2 = ak, mvv = av;
  #pragma unroll
  for (int off=16; off>=1; off>>=1){
    mq  = fmaxf(mq,  __shfl_xor(mq, off));
    mk2 = fmaxf(mk2, __shfl_xor(mk2,off));
    mvv = fmaxf(mvv, __shfl_xor(mvv,off));
  }
  float eq = expf(aq-mq), ek = expf(ak-mk2), ev = expf(av-mvv);
  float sq = eq, sk = ek, sv = ev;
  #pragma unroll
  for (int off=16; off>=1; off>>=1){
    sq += __shfl_xor(sq,off); sk += __shfl_xor(sk,off); sv += __shfl_xor(sv,off);
  }
  if (lane < 32){
    tQ[(size_t)token*32+n] = eq/sq;
    tK[(size_t)token*32+n] = ek/sk;
    tV[(size_t)token*32+n] = ev/sv;
  }
}

// ---------------- causal flash attention, 1 wave / 16-row q-tile, dh=64 ----------------
__global__ __launch_bounds__(64) void k_attn(const short* __restrict__ Qb, const short* __restrict__ Kb,
                                             const short* __restrict__ Vb, short* __restrict__ Ob)
{
  __shared__ short Ksm[2048];   // [32 kv][64 d]
  __shared__ short Vtsm[2048];  // [64 d][32 kv]
  __shared__ short Psm[512];    // [16 q][32 kv]
  int lane = threadIdx.x;
  int q0 = blockIdx.x << 4, h = blockIdx.y, b = blockIdx.z;
  size_t base = ((size_t)b*2048)*512 + h*64;
  s16x8 qf[2];
  {
    const short* qp = Qb + base + (size_t)(q0 + (lane&15))*512 + ((lane>>4)<<3);
    qf[0] = *(const s16x8*)(qp);
    qf[1] = *(const s16x8*)(qp + 32);
  }
  f32x4 o[4]; float mrow[4], lrow[4], alpha[4];
  #pragma unroll
  for (int i=0;i<4;i++){
    #pragma unroll
    for (int e=0;e<4;e++) o[i][e]=0.f;
    mrow[i]=-INFINITY; lrow[i]=0.f;
  }
  int kv_end = q0 + 16;
  for (int kv0 = 0; kv0 < kv_end; kv0 += 32){
    #pragma unroll
    for (int j=0;j<4;j++){
      int r = (j<<3) + (lane>>3);
      gload16(Kb + base + (size_t)(kv0 + r)*512 + ((lane&7)<<3), (char*)Ksm + j*1024);
      s16x8 vv = *(const s16x8*)(Vb + base + (size_t)(kv0 + r)*512 + ((lane&7)<<3));
      #pragma unroll
      for (int e=0;e<8;e++) Vtsm[(((lane&7)<<3) + e)*32 + r] = vv[e];
    }
    __syncthreads();
    f32x4 S0, S1;
    #pragma unroll
    for (int e=0;e<4;e++){ S0[e]=0.f; S1[e]=0.f; }
    #pragma unroll
    for (int kk=0;kk<2;kk++){
      s16x8 kf0 = *(const s16x8*)(Ksm + ((lane&15))*64 + kk*32 + ((lane>>4)<<3));
      s16x8 kf1 = *(const s16x8*)(Ksm + (16 + (lane&15))*64 + kk*32 + ((lane>>4)<<3));
      S0 = __builtin_amdgcn_mfma_f32_16x16x32_bf16(qf[kk], kf0, S0, 0,0,0);
      S1 = __builtin_amdgcn_mfma_f32_16x16x32_bf16(qf[kk], kf1, S1, 0,0,0);
    }
    #pragma unroll
    for (int e=0;e<4;e++){
      int q = q0 + ((lane>>4)<<2) + e;
      int kvA = kv0 + (lane&15);
      float s0 = S0[e]*0.125f;
      float s1 = S1[e]*0.125f;
      if (kvA > q)      s0 = -1e30f;
      if (kvA + 16 > q) s1 = -1e30f;
      float tm = fmaxf(s0, s1);
      #pragma unroll
      for (int off=1; off<16; off<<=1) tm = fmaxf(tm, __shfl_xor(tm, off));
      float mnew = fmaxf(mrow[e], tm);
      alpha[e] = expf(mrow[e] - mnew);
      float p0 = expf(s0 - mnew), p1 = expf(s1 - mnew);
      float ps = p0 + p1;
      #pragma unroll
      for (int off=1; off<16; off<<=1) ps += __shfl_xor(ps, off);
      lrow[e] = lrow[e]*alpha[e] + ps;
      mrow[e] = mnew;
      int prow = ((lane>>4)<<2) + e;
      Psm[prow*32 + (lane&15)]      = f2bf(p0);
      Psm[prow*32 + 16 + (lane&15)] = f2bf(p1);
    }
    __syncthreads();
    s16x8 pf = *(const s16x8*)(Psm + (lane&15)*32 + ((lane>>4)<<3));
    #pragma unroll
    for (int df=0; df<4; df++){
      s16x8 vf = *(const s16x8*)(Vtsm + (df*16 + (lane&15))*32 + ((lane>>4)<<3));
      f32x4 t;
      #pragma unroll
      for (int e=0;e<4;e++) t[e] = o[df][e]*alpha[e];
      o[df] = __builtin_amdgcn_mfma_f32_16x16x32_bf16(pf, vf, t, 0,0,0);
    }
    __syncthreads();
  }
  #pragma unroll
  for (int df=0; df<4; df++)
    #pragma unroll
    for (int e=0;e<4;e++){
      int q = q0 + ((lane>>4)<<2) + e;
      int d = df*16 + (lane&15);
      Ob[base + (size_t)q*512 + d] = f2bf(o[df][e] / lrow[e]);
    }
}

extern "C" void kernel_launch(void* const* d_in, const int* in_sizes, int n_in,
                              void* d_out, int out_size, void* d_ws, size_t ws_size,
                              hipStream_t stream)
{
  const float* x     = (const float*)d_in[0];
  const float* Wrt   = (const float*)d_in[1];
  const float* rQ    = (const float*)d_in[2];
  const float* rK    = (const float*)d_in[3];
  const float* rV    = (const float*)d_in[4];
  const float* basis = (const float*)d_in[5];
  const float* Wo    = (const float*)d_in[6];
  // d_in[7] = mask (causal tril; reproduced analytically)
  float* out = (float*)d_out;
  char* ws = (char*)d_ws;
  short* B2t  = (short*)(ws + 0);          // 32 MB  [16384][1024] bf16
  short* Xb   = (short*)(ws + 33554432);   // 16 MB  [8192][1024]  bf16
  float* SC   = (float*)(ws + 50331648);   // 16 MB  [8192][512]   f32
  float* tQ   = (float*)(ws + 67108864);   // 1 MB
  float* tK   = (float*)(ws + 68157440);   // 1 MB
  float* tV   = (float*)(ws + 69206016);   // 1 MB
  short* Qb   = (short*)(ws + 70254592);   // 8 MB   [8192][512] bf16
  short* Kb   = (short*)(ws + 78643200);   // 8 MB
  short* Vb   = (short*)(ws + 87031808);   // 8 MB
  short* Ob   = (short*)(ws + 95420416);   // 8 MB
  short* Wob  = (short*)(ws + 103809024);  // 1 MB   [1024][512] bf16
  short* Wrtb = (short*)(ws + 104857600);  // 1 MB   [512][1024] bf16
  float* oidx = out + 8388608;
  float* oww  = out + 8454144;

  hipFuncSetAttribute((const void*)k_pgemm8, hipFuncAttributeMaxDynamicSharedMemorySize, 131072);

  k_conv_bf16<<<8192, 256, 0, stream>>>(x, Xb, 2097152);
  k_conv_bf16<<<512, 256, 0, stream>>>(Wo, Wob, 131072);
  k_conv_bf16<<<512, 256, 0, stream>>>(Wrt, Wrtb, 131072);
  k_conv_basis<<<dim3(8,16,32), 256, 0, stream>>>(basis, B2t);
  // scores: SC[8192][512] = Xb @ Wrtb^T (approx, bf16)
  k_gemm_c32<<<256, 256, 0, stream>>>(Xb, Wrtb, 1024, 64, SC, 512);
  k_router<<<8192, 64, 0, stream>>>(SC, x, Wrt, rQ, rK, rV, tQ, tK, tV, oidx, oww);
  k_pgemm8<<<2048, 512, 131072, stream>>>(B2t, Xb, tQ, tK, tV, Qb, Kb, Vb);
  k_attn<<<dim3(128,8,4), 64, 0, stream>>>(Qb, Kb, Vb, Ob);
  // out[8192][1024] = Ob @ Wob^T
  k_gemm_c32<<<512, 256, 0, stream>>>(Ob, Wob, 512, 64, out, 1024);
}

// Round 6
// 590.476 us; speedup vs baseline: 2.3709x; 1.4575x over previous
//
#include <hip/hip_runtime.h>
#include <math.h>
#include <stdint.h>

// Problem constants
// B=4 S=2048 D=1024 N_NEURONS=512 K=8 N_BASIS=32 R=512 H=8 dh=64
// tokens T = 8192

typedef __attribute__((ext_vector_type(4))) float f32x4;
typedef __attribute__((ext_vector_type(8))) short s16x8;
typedef __attribute__((ext_vector_type(4))) short s16x4;

#define DEV __device__ __forceinline__

DEV short f2bf(float f){
  union { float f; unsigned u; } c; c.f = f;
  unsigned u = c.u;
  unsigned r = (u + 0x7fffu + ((u >> 16) & 1u)) >> 16;
  return (short)r;
}
DEV float bf2f(short s){
  union { unsigned u; float f; } c; c.u = ((unsigned)(unsigned short)s) << 16;
  return c.f;
}

typedef __attribute__((address_space(3))) void lds_vt;
typedef const __attribute__((address_space(1))) void g_vt;
DEV void gload16(const void* g, void* lds){
  __builtin_amdgcn_global_load_lds((g_vt*)g, (lds_vt*)lds, 16, 0, 0);
}

DEV void hard_barrier(){
  __builtin_amdgcn_sched_barrier(0);
  __builtin_amdgcn_s_barrier();
  __builtin_amdgcn_sched_barrier(0);
}

// ---------------- elementwise f32 -> bf16 ----------------
__global__ void k_conv_bf16(const float* __restrict__ in, short* __restrict__ out, int n4){
  int i = blockIdx.x*256 + threadIdx.x;
  if (i >= n4) return;
  float4 v = ((const float4*)in)[i];
  s16x4 o; o[0]=f2bf(v.x); o[1]=f2bf(v.y); o[2]=f2bf(v.z); o[3]=f2bf(v.w);
  ((s16x4*)out)[i] = o;
}

// ---------------- basis [32][1024][512] -> B2t bf16 [16384][1024], row c = r*32+n ----------------
__global__ __launch_bounds__(256) void k_conv_basis(const float* __restrict__ basis, short* __restrict__ B2t){
  __shared__ float tile[64][65];
  int tid = threadIdx.x;
  int r0 = blockIdx.x<<6, d0 = blockIdx.y<<6, n = blockIdx.z;
  const float* src = basis + ((size_t)n*1024 + d0)*512 + r0;
  for (int i = tid; i < 4096; i += 256){ int dd = i>>6, rr = i&63; tile[dd][rr] = src[(size_t)dd*512 + rr]; }
  __syncthreads();
  for (int i = tid; i < 4096; i += 256){ int rr = i>>6, dd = i&63;
    B2t[((size_t)(r0+rr)*32 + n)*1024 + d0 + dd] = f2bf(tile[dd][rr]); }
}

// ---------------- bf16 MFMA GEMM 128x128xBK64 -> f32 C (scores, W_o) ----------------
__global__ __launch_bounds__(256) void k_gemm_c32(
    const short* __restrict__ A, const short* __restrict__ Bt, int Kd, int Mblk,
    float* __restrict__ C, int ldc)
{
  __shared__ char smem[32768];
  short* Asm = (short*)smem;
  short* Bsm = (short*)(smem + 16384);
  int tid = threadIdx.x, lane = tid & 63, w = tid >> 6;
  int wr = w >> 1, wc = w & 1;
  int nwg = gridDim.x, bid = blockIdx.x;
  int sid = (bid & 7) * (nwg >> 3) + (bid >> 3);
  int row0 = (sid % Mblk) << 7;
  int col0 = (sid / Mblk) << 7;
  f32x4 acc[4][4];
  #pragma unroll
  for (int m=0;m<4;m++)
    #pragma unroll
    for (int nf=0;nf<4;nf++)
      #pragma unroll
      for (int e=0;e<4;e++) acc[m][nf][e] = 0.f;
  int lr8 = lane >> 3;
  int lk_sw = (((lane & 7) ^ (lane >> 3)) << 3);
  for (int k0 = 0; k0 < Kd; k0 += 64){
    #pragma unroll
    for (int i=0;i<4;i++){
      int chunk = (w<<2) + i;
      int r = (chunk<<3) + lr8;
      gload16(A  + (size_t)(row0 + r)*Kd + k0 + lk_sw, smem + chunk*1024);
      gload16(Bt + (size_t)(col0 + r)*Kd + k0 + lk_sw, smem + 16384 + chunk*1024);
    }
    __syncthreads();
    #pragma unroll
    for (int kk=0; kk<2; kk++){
      int csw = (kk*32 + ((lane>>4)<<3)) ^ ((lane & 7) << 3);
      s16x8 af[4], bfr[4];
      #pragma unroll
      for (int m=0;m<4;m++)
        af[m] = *(const s16x8*)(Asm + ((wr*64 + m*16 + (lane&15))*64 + csw));
      #pragma unroll
      for (int nf=0;nf<4;nf++)
        bfr[nf] = *(const s16x8*)(Bsm + ((wc*64 + nf*16 + (lane&15))*64 + csw));
      #pragma unroll
      for (int m=0;m<4;m++)
        #pragma unroll
        for (int nf=0;nf<4;nf++)
          acc[m][nf] = __builtin_amdgcn_mfma_f32_16x16x32_bf16(af[m], bfr[nf], acc[m][nf], 0, 0, 0);
    }
    __syncthreads();
  }
  #pragma unroll
  for (int m=0;m<4;m++)
    #pragma unroll
    for (int nf=0;nf<4;nf++)
      #pragma unroll
      for (int e=0;e<4;e++){
        int tok = wr*64 + m*16 + ((lane>>4)<<2) + e;
        int col = wc*64 + nf*16 + (lane&15);
        C[(size_t)(row0+tok)*ldc + col0 + col] = acc[m][nf][e];
      }
}

// ---------------- fused P-GEMM, 256x256 8-phase deep pipeline ----------------
// C[c = r*32+n][tok] = B2t[16384][1024] @ Xb[8192][1024]^T, fused n-contract -> Q/K bf16 + V^T.
#define STAGE(G, tileRow0, half, tkt, bufOff) do{ \
  char* _d = smem + (bufOff) + (((tkt)&1)*32768) + ((half)*16384) + (wid*2048); \
  const short* _s = (G) + (size_t)((tileRow0) + (half)*128 + wid*16 + (lane>>3))*1024 + ((tkt)<<6) + (((lane&7)^(lane>>3))<<3); \
  gload16(_s, _d); \
  gload16(_s + 8192, _d + 1024); \
}while(0)

#define LDA(MOFF) \
  _Pragma("unroll") \
  for (int i=0;i<4;i++){ \
    const char* _p = Acur + ((MOFF) + i*16 + l15)*128; \
    _Pragma("unroll") \
    for (int kk=0;kk<2;kk++) \
      af[i][kk] = *(const s16x8*)(_p + ((((kk<<2)+g16) ^ l7)<<4)); \
  }

#define LDB(N0) \
  _Pragma("unroll") \
  for (int n=0;n<2;n++){ \
    const char* _p = Bcur + (((wc&1)*64) + ((N0)+n)*16 + l15)*128; \
    _Pragma("unroll") \
    for (int kk=0;kk<2;kk++) \
      bf_[(N0)+n][kk] = *(const s16x8*)(_p + ((((kk<<2)+g16) ^ l7)<<4)); \
  }

#define LGKM0() do{ \
  asm volatile("s_waitcnt lgkmcnt(0)" ::: "memory"); \
  __builtin_amdgcn_sched_barrier(0); \
}while(0)

#define MFMA_QUAD(MB, NB) do{ \
  __builtin_amdgcn_s_setprio(1); \
  _Pragma("unroll") \
  for (int kk=0;kk<2;kk++) \
    _Pragma("unroll") \
    for (int i=0;i<4;i++) \
      _Pragma("unroll") \
      for (int n=0;n<2;n++) \
        acc[(MB)+i][(NB)+n] = __builtin_amdgcn_mfma_f32_16x16x32_bf16(af[i][kk], bf_[(NB)+n][kk], acc[(MB)+i][(NB)+n], 0,0,0); \
  __builtin_amdgcn_s_setprio(0); \
}while(0)

__global__ __launch_bounds__(512, 2) void k_pgemm8(
    const short* __restrict__ B2t, const short* __restrict__ Xb,
    const float* __restrict__ tQp, const float* __restrict__ tKp, const float* __restrict__ tVp,
    short* __restrict__ Qb, short* __restrict__ Kb, short* __restrict__ Vt)
{
  extern __shared__ char smem[];
  int tid = threadIdx.x, lane = tid & 63, wid = tid >> 6;
  int wr = wid >> 2, wc = wid & 3;
  int l15 = lane & 15, l7 = lane & 7, g16 = lane >> 4;
  int bid = blockIdx.x;
  int xcd = bid & 7, lid = bid >> 3;        // lid 0..255
  int t_tile = (xcd << 2) + (lid & 3);      // 0..31
  int c_tile = lid >> 2;                    // 0..63
  int row0 = c_tile << 8;                   // B2t row base
  int col0 = t_tile << 8;                   // token base

  f32x4 acc[8][4];
  #pragma unroll
  for (int m=0;m<8;m++)
    #pragma unroll
    for (int n=0;n<4;n++)
      #pragma unroll
      for (int e=0;e<4;e++) acc[m][n][e] = 0.f;
  s16x8 af[4][2], bf_[4][2];

  STAGE(B2t, row0, 0, 0, 0);
  STAGE(B2t, row0, 1, 0, 0);
  STAGE(Xb,  col0, 0, 0, 65536);
  STAGE(Xb,  col0, 1, 0, 65536);
  STAGE(B2t, row0, 0, 1, 0);
  asm volatile("s_waitcnt vmcnt(2)" ::: "memory");
  hard_barrier();

  for (int kt = 0; kt < 16; ++kt){
    const int cur = kt & 1;
    const char* Acur = smem + cur*32768 + wr*16384;
    const char* Bcur = smem + 65536 + cur*32768 + ((wc>>1)*16384);
    LDA(0); LDB(0);
    if (kt < 15) STAGE(B2t, row0, 1, kt+1, 0);
    hard_barrier();
    LGKM0();
    MFMA_QUAD(0, 0);
    hard_barrier();
    LDB(2);
    if (kt < 15) STAGE(Xb, col0, 0, kt+1, 65536);
    hard_barrier();
    LGKM0();
    MFMA_QUAD(0, 2);
    hard_barrier();
    LDA(64);
    if (kt < 15) STAGE(Xb, col0, 1, kt+1, 65536);
    hard_barrier();
    LGKM0();
    MFMA_QUAD(4, 0);
    hard_barrier();
    if (kt < 14) STAGE(B2t, row0, 0, kt+2, 0);
    MFMA_QUAD(4, 2);
    asm volatile("s_waitcnt vmcnt(2)" ::: "memory");
    hard_barrier();
  }

  // ---- fused epilogue: Q/K[tok][r], V^T[b][h][d][s] = sum_n C[r*32+n][tok]*t[tok][n] ----
  __syncthreads();
  short* t16 = (short*)smem;    // [3][256 tok][36] bf16
  for (int i = tid; i < 8192; i += 512){
    int tk = i >> 5, n = i & 31;
    t16[tk*36 + n]            = f2bf(tQp[(size_t)col0*32 + i]);
    t16[9216 + tk*36 + n]     = f2bf(tKp[(size_t)col0*32 + i]);
    t16[18432 + tk*36 + n]    = f2bf(tVp[(size_t)col0*32 + i]);
  }
  __syncthreads();
  int g4 = g16 << 2, tokl = l15;
  int rb = (row0 >> 5) + (wr << 2);
  #pragma unroll
  for (int rec=0; rec<3; rec++){
    const short* tb = t16 + rec*9216;
    #pragma unroll
    for (int nf=0;nf<4;nf++){
      int tok = wc*64 + nf*16 + tokl;
      s16x4 tlo = *(const s16x4*)(tb + tok*36 + g4);
      s16x4 thi = *(const s16x4*)(tb + tok*36 + 16 + g4);
      #pragma unroll
      for (int mp=0;mp<4;mp++){
        float p = 0.f;
        #pragma unroll
        for (int e=0;e<4;e++) p += acc[2*mp][nf][e]   * bf2f(tlo[e]);
        #pragma unroll
        for (int e=0;e<4;e++) p += acc[2*mp+1][nf][e] * bf2f(thi[e]);
        p += __shfl_xor(p, 16);
        p += __shfl_xor(p, 32);
        if (g16 == rec){
          int gtok = col0 + tok;
          int r = rb + mp;
          if (rec == 0)      Qb[(size_t)gtok*512 + r] = f2bf(p);
          else if (rec == 1) Kb[(size_t)gtok*512 + r] = f2bf(p);
          else Vt[(((size_t)(gtok>>11)*8 + (r>>6))*64 + (r&63))*2048 + (gtok&2047)] = f2bf(p);
        }
      }
    }
  }
}

// ---------------- router: bf16-MFMA scores -> top-32 candidates -> f64 exact rescore -> top-8 ----------------
__global__ __launch_bounds__(64) void k_router(const float* __restrict__ scores,
    const float* __restrict__ X, const float* __restrict__ W,
    const float* __restrict__ rQ, const float* __restrict__ rK, const float* __restrict__ rV,
    float* __restrict__ tQ, float* __restrict__ tK, float* __restrict__ tV,
    float* __restrict__ oidx, float* __restrict__ ow){
  int token = blockIdx.x; int lane = threadIdx.x;
  const float* srow = scores + (size_t)token*512;
  float v[8];
  #pragma unroll
  for (int j=0;j<8;j++) v[j] = srow[lane + 64*j];
  int myidx = 0x7fffffff;
  #pragma unroll
  for (int k=0;k<32;k++){
    float bm = -INFINITY; int bi = 0x7fffffff;
    #pragma unroll
    for (int j=0;j<8;j++){ if (v[j] > bm) { bm = v[j]; bi = lane + 64*j; } }
    #pragma unroll
    for (int off=32; off>=1; off>>=1){
      float om = __shfl_xor(bm, off); int oi = __shfl_xor(bi, off);
      if (om > bm || (om == bm && oi < bi)) { bm = om; bi = oi; }
    }
    if (lane == k) myidx = bi;
    #pragma unroll
    for (int j=0;j<8;j++) if (lane + 64*j == bi) v[j] = -INFINITY;
  }
  float xr[16];
  {
    const float4* x4 = (const float4*)(X + (size_t)token*1024 + lane*16);
    #pragma unroll
    for (int q=0;q<4;q++){ float4 t = x4[q]; xr[q*4]=t.x; xr[q*4+1]=t.y; xr[q*4+2]=t.z; xr[q*4+3]=t.w; }
  }
  double myref = -1e300;
  #pragma unroll
  for (int c=0;c<32;c++){
    int nid = __shfl(myidx, c);
    const float4* w4 = (const float4*)(W + (size_t)nid*1024 + lane*16);
    double acc = 0.0;
    #pragma unroll
    for (int q=0;q<4;q++){
      float4 t = w4[q];
      acc += (double)xr[q*4]   * (double)t.x;
      acc += (double)xr[q*4+1] * (double)t.y;
      acc += (double)xr[q*4+2] * (double)t.z;
      acc += (double)xr[q*4+3] * (double)t.w;
    }
    #pragma unroll
    for (int off=32; off>=1; off>>=1) acc += __shfl_xor(acc, off);
    if (lane == c) myref = acc;
  }
  double mv = myref; int mi = myidx;
  double topv[8]; int topi[8];
  #pragma unroll
  for (int k=0;k<8;k++){
    double bm = mv; int bi = mi;
    #pragma unroll
    for (int off=32; off>=1; off>>=1){
      double om = __shfl_xor(bm, off); int oi = __shfl_xor(bi, off);
      if (om > bm || (om == bm && oi < bi)) { bm = om; bi = oi; }
    }
    topv[k]=bm; topi[k]=bi;
    if (mi == bi) mv = -1e300;
  }
  double mx = topv[0]; double s = 0.0; double wd[8];
  #pragma unroll
  for (int k=0;k<8;k++){ wd[k] = exp(topv[k]-mx); s += wd[k]; }
  float w[8];
  #pragma unroll
  for (int k=0;k<8;k++) w[k] = (float)(wd[k]/s);
  if (lane == 0){
    #pragma unroll
    for (int k=0;k<8;k++){ oidx[(size_t)token*8+k] = (float)topi[k]; ow[(size_t)token*8+k] = w[k]; }
  }
  int n = lane & 31;
  float aq=0.f, ak=0.f, av=0.f;
  #pragma unroll
  for (int k=0;k<8;k++){
    size_t off = (size_t)topi[k]*32 + n;
    aq += w[k]*rQ[off]; ak += w[k]*rK[off]; av += w[k]*rV[off];
  }
  float mq = aq, mk2 = ak, mvv = av;
  #pragma unroll
  for (int off=16; off>=1; off>>=1){
    mq  = fmaxf(mq,  __shfl_xor(mq, off));
    mk2 = fmaxf(mk2, __shfl_xor(mk2,off));
    mvv = fmaxf(mvv, __shfl_xor(mvv,off));
  }
  float eq = expf(aq-mq), ek = expf(ak-mk2), ev = expf(av-mvv);
  float sq = eq, sk = ek, sv = ev;
  #pragma unroll
  for (int off=16; off>=1; off>>=1){
    sq += __shfl_xor(sq,off); sk += __shfl_xor(sk,off); sv += __shfl_xor(sv,off);
  }
  if (lane < 32){
    tQ[(size_t)token*32+n] = eq/sq;
    tK[(size_t)token*32+n] = ek/sk;
    tV[(size_t)token*32+n] = ev/sv;
  }
}

// ---------------- causal flash attention: 4 waves, QBLK=64, KVBLK=64, swizzled LDS ----------------
// Vt layout: [b][h][64 d][2048 s]. Grid: 1024 blocks x 256 thr.
__global__ __launch_bounds__(256) void k_attn(const short* __restrict__ Qb, const short* __restrict__ Kb,
                                              const short* __restrict__ Vt, short* __restrict__ Ob)
{
  __shared__ char smem[40960];  // K[2][8KB] @0, Vt[2][8KB] @16384, P[4][2KB] @32768
  int tid = threadIdx.x, lane = tid & 63, wid = tid >> 6;
  int l15 = lane & 15, l7 = lane & 7, g16 = lane >> 4;
  int bid = blockIdx.x;
  int xcd = bid & 7, lid = bid >> 3;
  int work = xcd*128 + lid;              // XCD-chunked: 4 (b,h) per XCD
  int bx = 31 - (work & 31);             // big (diagonal-heavy) blocks first
  int bh = work >> 5; int h = bh & 7, b = bh >> 3;
  size_t tokbase = (size_t)b*2048;
  int q0 = bx << 6;
  int nt = bx + 1;

#define ATTN_STAGE(kt_) do{ \
  int _c = (kt_) & 1; \
  _Pragma("unroll") \
  for (int _i=0;_i<2;_i++){ \
    int _row = _i*32 + (wid<<3) + (lane>>3); \
    gload16(Kb + (tokbase + (((kt_)<<6) + _row))*512 + (h<<6) + ((l7 ^ (_row&7))<<3), \
            smem + (_c<<13) + _i*4096 + (wid<<10) + lane*16); \
    gload16(Vt + (size_t)((bh<<6) + _row)*2048 + ((kt_)<<6) + ((l7 ^ (_row&7))<<3), \
            smem + 16384 + (_c<<13) + _i*4096 + (wid<<10) + lane*16); \
  } \
}while(0)

  // Q fragments (A-operand rows = q)
  s16x8 qf[2];
  {
    const short* qp = Qb + (tokbase + q0 + wid*16 + l15)*512 + (h<<6);
    qf[0] = *(const s16x8*)(qp + g16*8);
    qf[1] = *(const s16x8*)(qp + 32 + g16*8);
  }
  f32x4 o[4]; float mrow[4], lrow[4];
  #pragma unroll
  for (int i=0;i<4;i++){
    #pragma unroll
    for (int e=0;e<4;e++) o[i][e]=0.f;
    mrow[i]=-INFINITY; lrow[i]=0.f;
  }

  ATTN_STAGE(0);
  __syncthreads();

  for (int kt = 0; kt < nt; ++kt){
    if (kt + 1 < nt) ATTN_STAGE(kt+1);
    int cur = kt & 1;
    const char* Kc = smem + (cur<<13);
    const char* Vc = smem + 16384 + (cur<<13);
    short* Pw16 = (short*)(smem + 32768 + (wid<<11));
    // ---- QK^T: S[s16] covers kv subtile s16*16..+15 ----
    f32x4 S[4];
    #pragma unroll
    for (int s16=0;s16<4;s16++){
      #pragma unroll
      for (int e=0;e<4;e++) S[s16][e] = 0.f;
      const char* kr = Kc + (s16*16 + l15)*128;
      s16x8 kf0 = *(const s16x8*)(kr + (((g16  ) ^ l7)<<4));
      s16x8 kf1 = *(const s16x8*)(kr + (((4+g16) ^ l7)<<4));
      S[s16] = __builtin_amdgcn_mfma_f32_16x16x32_bf16(qf[0], kf0, S[s16], 0,0,0);
      S[s16] = __builtin_amdgcn_mfma_f32_16x16x32_bf16(qf[1], kf1, S[s16], 0,0,0);
    }
    // ---- online softmax (per lane: q = q0+wid*16+g16*4+e, kv = s16*16+l15) ----
    bool diag = (kt == nt-1);
    #pragma unroll
    for (int e=0;e<4;e++){
      float sv0 = S[0][e]*0.125f, sv1 = S[1][e]*0.125f;
      float sv2 = S[2][e]*0.125f, sv3 = S[3][e]*0.125f;
      if (diag){
        int q_abs = q0 + wid*16 + (g16<<2) + e;
        int kvb = (kt<<6) + l15;
        if (kvb      > q_abs) sv0 = -1e30f;
        if (kvb + 16 > q_abs) sv1 = -1e30f;
        if (kvb + 32 > q_abs) sv2 = -1e30f;
        if (kvb + 48 > q_abs) sv3 = -1e30f;
      }
      float tm = fmaxf(fmaxf(sv0,sv1), fmaxf(sv2,sv3));
      #pragma unroll
      for (int off=1; off<16; off<<=1) tm = fmaxf(tm, __shfl_xor(tm, off));
      float mnew = fmaxf(mrow[e], tm);
      float alpha = expf(mrow[e] - mnew);
      mrow[e] = mnew;
      float p0 = expf(sv0-mnew), p1 = expf(sv1-mnew);
      float p2 = expf(sv2-mnew), p3 = expf(sv3-mnew);
      float ps = (p0+p1) + (p2+p3);
      #pragma unroll
      for (int off=1; off<16; off<<=1) ps += __shfl_xor(ps, off);
      lrow[e] = lrow[e]*alpha + ps;
      #pragma unroll
      for (int df=0;df<4;df++) o[df][e] *= alpha;
      int prow = (g16<<2) + e;
      int pbase = prow*64; int pr7 = prow & 7;
      int g0 = l15 >> 3, w2 = l15 & 7;
      Pw16[pbase + (((g0  ) ^ pr7)<<3) + w2] = f2bf(p0);
      Pw16[pbase + (((2+g0) ^ pr7)<<3) + w2] = f2bf(p1);
      Pw16[pbase + (((4+g0) ^ pr7)<<3) + w2] = f2bf(p2);
      Pw16[pbase + (((6+g0) ^ pr7)<<3) + w2] = f2bf(p3);
    }
    // ---- PV: o[df] += P(16q x 64kv) @ V^T(64d x 64kv)^T ----
    const char* Pb = (const char*)Pw16;
    s16x8 pf0 = *(const s16x8*)(Pb + l15*128 + (((g16  ) ^ l7)<<4));
    s16x8 pf1 = *(const s16x8*)(Pb + l15*128 + (((4+g16) ^ l7)<<4));
    #pragma unroll
    for (int df=0;df<4;df++){
      const char* vr = Vc + (df*16 + l15)*128;
      s16x8 vf0 = *(const s16x8*)(vr + (((g16  ) ^ l7)<<4));
      s16x8 vf1 = *(const s16x8*)(vr + (((4+g16) ^ l7)<<4));
      o[df] = __builtin_amdgcn_mfma_f32_16x16x32_bf16(pf0, vf0, o[df], 0,0,0);
      o[df] = __builtin_amdgcn_mfma_f32_16x16x32_bf16(pf1, vf1, o[df], 0,0,0);
    }
    __syncthreads();
  }
  #pragma unroll
  for (int df=0;df<4;df++)
    #pragma unroll
    for (int e=0;e<4;e++){
      int q = q0 + wid*16 + (g16<<2) + e;
      int d = df*16 + l15;
      Ob[(tokbase + q)*512 + (h<<6) + d] = f2bf(o[df][e] / lrow[e]);
    }
#undef ATTN_STAGE
}

extern "C" void kernel_launch(void* const* d_in, const int* in_sizes, int n_in,
                              void* d_out, int out_size, void* d_ws, size_t ws_size,
                              hipStream_t stream)
{
  const float* x     = (const float*)d_in[0];
  const float* Wrt   = (const float*)d_in[1];
  const float* rQ    = (const float*)d_in[2];
  const float* rK    = (const float*)d_in[3];
  const float* rV    = (const float*)d_in[4];
  const float* basis = (const float*)d_in[5];
  const float* Wo    = (const float*)d_in[6];
  // d_in[7] = mask (causal tril; reproduced analytically)
  float* out = (float*)d_out;
  char* ws = (char*)d_ws;
  short* B2t  = (short*)(ws + 0);          // 32 MB  [16384][1024] bf16
  short* Xb   = (short*)(ws + 33554432);   // 16 MB  [8192][1024]  bf16
  float* SC   = (float*)(ws + 50331648);   // 16 MB  [8192][512]   f32
  float* tQ   = (float*)(ws + 67108864);   // 1 MB
  float* tK   = (float*)(ws + 68157440);   // 1 MB
  float* tV   = (float*)(ws + 69206016);   // 1 MB
  short* Qb   = (short*)(ws + 70254592);   // 8 MB   [8192][512] bf16
  short* Kb   = (short*)(ws + 78643200);   // 8 MB
  short* Vt   = (short*)(ws + 87031808);   // 8 MB   [4][8][64][2048] bf16 (V transposed)
  short* Ob   = (short*)(ws + 95420416);   // 8 MB
  short* Wob  = (short*)(ws + 103809024);  // 1 MB   [1024][512] bf16
  short* Wrtb = (short*)(ws + 104857600);  // 1 MB   [512][1024] bf16
  float* oidx = out + 8388608;
  float* oww  = out + 8454144;

  hipFuncSetAttribute((const void*)k_pgemm8, hipFuncAttributeMaxDynamicSharedMemorySize, 131072);

  k_conv_bf16<<<8192, 256, 0, stream>>>(x, Xb, 2097152);
  k_conv_bf16<<<512, 256, 0, stream>>>(Wo, Wob, 131072);
  k_conv_bf16<<<512, 256, 0, stream>>>(Wrt, Wrtb, 131072);
  k_conv_basis<<<dim3(8,16,32), 256, 0, stream>>>(basis, B2t);
  // scores: SC[8192][512] = Xb @ Wrtb^T (approx, bf16)
  k_gemm_c32<<<256, 256, 0, stream>>>(Xb, Wrtb, 1024, 64, SC, 512);
  k_router<<<8192, 64, 0, stream>>>(SC, x, Wrt, rQ, rK, rV, tQ, tK, tV, oidx, oww);
  k_pgemm8<<<2048, 512, 131072, stream>>>(B2t, Xb, tQ, tK, tV, Qb, Kb, Vt);
  k_attn<<<1024, 256, 0, stream>>>(Qb, Kb, Vt, Ob);
  // out[8192][1024] = Ob @ Wob^T
  k_gemm_c32<<<512, 256, 0, stream>>>(Ob, Wob, 512, 64, out, 1024);
}

// Round 7
// 590.357 us; speedup vs baseline: 2.3713x; 1.0002x over previous
//
#include <hip/hip_runtime.h>
#include <math.h>
#include <stdint.h>

// Problem constants
// B=4 S=2048 D=1024 N_NEURONS=512 K=8 N_BASIS=32 R=512 H=8 dh=64
// tokens T = 8192

typedef __attribute__((ext_vector_type(4))) float f32x4;
typedef __attribute__((ext_vector_type(8))) short s16x8;
typedef __attribute__((ext_vector_type(4))) short s16x4;

#define DEV __device__ __forceinline__

DEV short f2bf(float f){
  union { float f; unsigned u; } c; c.f = f;
  unsigned u = c.u;
  unsigned r = (u + 0x7fffu + ((u >> 16) & 1u)) >> 16;
  return (short)r;
}
DEV float bf2f(short s){
  union { unsigned u; float f; } c; c.u = ((unsigned)(unsigned short)s) << 16;
  return c.f;
}

typedef __attribute__((address_space(3))) void lds_vt;
typedef const __attribute__((address_space(1))) void g_vt;
DEV void gload16(const void* g, void* lds){
  __builtin_amdgcn_global_load_lds((g_vt*)g, (lds_vt*)lds, 16, 0, 0);
}

DEV void hard_barrier(){
  __builtin_amdgcn_sched_barrier(0);
  __builtin_amdgcn_s_barrier();
  __builtin_amdgcn_sched_barrier(0);
}

// ---------------- elementwise f32 -> bf16 ----------------
__global__ void k_conv_bf16(const float* __restrict__ in, short* __restrict__ out, int n4){
  int i = blockIdx.x*256 + threadIdx.x;
  if (i >= n4) return;
  float4 v = ((const float4*)in)[i];
  s16x4 o; o[0]=f2bf(v.x); o[1]=f2bf(v.y); o[2]=f2bf(v.z); o[3]=f2bf(v.w);
  ((s16x4*)out)[i] = o;
}

// ---------------- basis [32][1024][512] -> B2t bf16 [16384][1024], row c = r*32+n ----------------
__global__ __launch_bounds__(256) void k_conv_basis(const float* __restrict__ basis, short* __restrict__ B2t){
  __shared__ float tile[64][65];
  int tid = threadIdx.x;
  int r0 = blockIdx.x<<6, d0 = blockIdx.y<<6, n = blockIdx.z;
  const float* src = basis + ((size_t)n*1024 + d0)*512 + r0;
  for (int i = tid; i < 4096; i += 256){ int dd = i>>6, rr = i&63; tile[dd][rr] = src[(size_t)dd*512 + rr]; }
  __syncthreads();
  for (int i = tid; i < 4096; i += 256){ int rr = i>>6, dd = i&63;
    B2t[((size_t)(r0+rr)*32 + n)*1024 + d0 + dd] = f2bf(tile[dd][rr]); }
}

// ---------------- bf16 MFMA GEMM 128x128xBK64 -> f32 C (scores, W_o) ----------------
__global__ __launch_bounds__(256) void k_gemm_c32(
    const short* __restrict__ A, const short* __restrict__ Bt, int Kd, int Mblk,
    float* __restrict__ C, int ldc)
{
  __shared__ char smem[32768];
  short* Asm = (short*)smem;
  short* Bsm = (short*)(smem + 16384);
  int tid = threadIdx.x, lane = tid & 63, w = tid >> 6;
  int wr = w >> 1, wc = w & 1;
  int nwg = gridDim.x, bid = blockIdx.x;
  int sid = (bid & 7) * (nwg >> 3) + (bid >> 3);
  int row0 = (sid % Mblk) << 7;
  int col0 = (sid / Mblk) << 7;
  f32x4 acc[4][4];
  #pragma unroll
  for (int m=0;m<4;m++)
    #pragma unroll
    for (int nf=0;nf<4;nf++)
      #pragma unroll
      for (int e=0;e<4;e++) acc[m][nf][e] = 0.f;
  int lr8 = lane >> 3;
  int lk_sw = (((lane & 7) ^ (lane >> 3)) << 3);
  for (int k0 = 0; k0 < Kd; k0 += 64){
    #pragma unroll
    for (int i=0;i<4;i++){
      int chunk = (w<<2) + i;
      int r = (chunk<<3) + lr8;
      gload16(A  + (size_t)(row0 + r)*Kd + k0 + lk_sw, smem + chunk*1024);
      gload16(Bt + (size_t)(col0 + r)*Kd + k0 + lk_sw, smem + 16384 + chunk*1024);
    }
    __syncthreads();
    #pragma unroll
    for (int kk=0; kk<2; kk++){
      int csw = (kk*32 + ((lane>>4)<<3)) ^ ((lane & 7) << 3);
      s16x8 af[4], bfr[4];
      #pragma unroll
      for (int m=0;m<4;m++)
        af[m] = *(const s16x8*)(Asm + ((wr*64 + m*16 + (lane&15))*64 + csw));
      #pragma unroll
      for (int nf=0;nf<4;nf++)
        bfr[nf] = *(const s16x8*)(Bsm + ((wc*64 + nf*16 + (lane&15))*64 + csw));
      #pragma unroll
      for (int m=0;m<4;m++)
        #pragma unroll
        for (int nf=0;nf<4;nf++)
          acc[m][nf] = __builtin_amdgcn_mfma_f32_16x16x32_bf16(af[m], bfr[nf], acc[m][nf], 0, 0, 0);
    }
    __syncthreads();
  }
  #pragma unroll
  for (int m=0;m<4;m++)
    #pragma unroll
    for (int nf=0;nf<4;nf++)
      #pragma unroll
      for (int e=0;e<4;e++){
        int tok = wr*64 + m*16 + ((lane>>4)<<2) + e;
        int col = wc*64 + nf*16 + (lane&15);
        C[(size_t)(row0+tok)*ldc + col0 + col] = acc[m][nf][e];
      }
}

// ---------------- fused P-GEMM, 256x256, quadrant-role 4-phase deep pipeline ----------------
// C[c = r*32+n][tok] = B2t @ Xb^T, fused n-contract -> Q/K bf16 + V^T.
// 8 waves; per phase ALL waves compute one C-quadrant (wave-sub 64x32).
// LDS 128 KiB: A[2buf][2half(M)][128][64]bf16 @0, B[2buf][2half(tok)][128][64] @65536.
// Stage slots: ph0:B-h1(kt+1) ph1:A-h1(kt+1) ph2:A-h0(kt+2) ph3:B-h0(kt+2) (clamped at tail).
// vmcnt(6)/vmcnt(6)/vmcnt(4) counted waits; frag ds_reads issued one phase early.
#define STAGE(G, tileRow0, half, tkt) do{ \
  int _t = (tkt) < 15 ? (tkt) : 15; \
  char* _d = smem + ((G)==Xb ? 65536 : 0) + ((_t&1)*32768) + ((half)*16384) + (wid*2048); \
  const short* _s = (G) + (size_t)((tileRow0) + (half)*128 + wid*16 + (lane>>3))*1024 + (_t<<6) + (((lane&7)^(lane>>3))<<3); \
  gload16(_s, _d); \
  gload16(_s + 8192, _d + 1024); \
}while(0)

#define LD_AF(dst, base) \
  _Pragma("unroll") \
  for (int i=0;i<4;i++){ \
    const char* _p = (base) + (wm*64 + i*16 + l15)*128; \
    _Pragma("unroll") \
    for (int kk=0;kk<2;kk++) \
      dst[i][kk] = *(const s16x8*)(_p + ((((kk<<2)+g16) ^ l7)<<4)); \
  }

#define LD_BF(dst, base) \
  _Pragma("unroll") \
  for (int n=0;n<2;n++){ \
    const char* _p = (base) + (wn*32 + n*16 + l15)*128; \
    _Pragma("unroll") \
    for (int kk=0;kk<2;kk++) \
      dst[n][kk] = *(const s16x8*)(_p + ((((kk<<2)+g16) ^ l7)<<4)); \
  }

#define MFMA_Q(Q, AF, BF) do{ \
  __builtin_amdgcn_s_setprio(1); \
  _Pragma("unroll") \
  for (int kk=0;kk<2;kk++) \
    _Pragma("unroll") \
    for (int i=0;i<4;i++) \
      _Pragma("unroll") \
      for (int n=0;n<2;n++) \
        acc[Q][i][n] = __builtin_amdgcn_mfma_f32_16x16x32_bf16(AF[i][kk], BF[n][kk], acc[Q][i][n], 0,0,0); \
  __builtin_amdgcn_s_setprio(0); \
}while(0)

__global__ __launch_bounds__(512, 2) void k_pgemm8(
    const short* __restrict__ B2t, const short* __restrict__ Xb,
    const float* __restrict__ tQp, const float* __restrict__ tKp, const float* __restrict__ tVp,
    short* __restrict__ Qb, short* __restrict__ Kb, short* __restrict__ Vt)
{
  extern __shared__ char smem[];
  int tid = threadIdx.x, lane = tid & 63, wid = tid >> 6;
  int wm = wid >> 2, wn = wid & 3;
  int l15 = lane & 15, l7 = lane & 7, g16 = lane >> 4;
  int bid = blockIdx.x;
  int xcd = bid & 7, lid = bid >> 3;        // lid 0..255
  int t_tile = (xcd << 2) + (lid & 3);      // 0..31
  int c_tile = lid >> 2;                    // 0..63
  int row0 = c_tile << 8;                   // B2t row base
  int col0 = t_tile << 8;                   // token base

  f32x4 acc[4][4][2];                       // [quadrant][m][n]
  #pragma unroll
  for (int q=0;q<4;q++)
    #pragma unroll
    for (int m=0;m<4;m++)
      #pragma unroll
      for (int n=0;n<2;n++)
        #pragma unroll
        for (int e=0;e<4;e++) acc[q][m][n][e] = 0.f;
  s16x8 af_a[4][2], af_b[4][2], bf_a[2][2], bf_b[2][2];

  // prologue: tile0 all 4 halves, then tile1 A-h0,B-h0
  STAGE(B2t, row0, 0, 0);
  STAGE(Xb,  col0, 0, 0);
  STAGE(B2t, row0, 1, 0);
  STAGE(Xb,  col0, 1, 0);
  STAGE(B2t, row0, 0, 1);
  STAGE(Xb,  col0, 0, 1);
  asm volatile("s_waitcnt vmcnt(4)" ::: "memory");
  hard_barrier();
  LD_AF(af_a, smem);                         // A-h0 tile0 (buf0)
  LD_BF(bf_a, smem + 65536);                 // B-h0 tile0 (buf0)

  for (int kt = 0; kt < 16; ++kt){
    const int cur = kt & 1;
    const char* Ac = smem + cur*32768;
    const char* Bc = smem + 65536 + cur*32768;
    const char* An = smem + (cur^1)*32768;
    const char* Bn = smem + 65536 + (cur^1)*32768;
    // ---- ph0: Q0 = (M-h0 x N-h0) ----
    asm volatile("s_waitcnt vmcnt(6)" ::: "memory");
    LD_BF(bf_b, Bc + 16384);                 // B-h1(kt)
    STAGE(Xb, col0, 1, kt+1);
    hard_barrier();
    MFMA_Q(0, af_a, bf_a);
    hard_barrier();
    // ---- ph1: Q1 = (M-h0 x N-h1) ----
    asm volatile("s_waitcnt vmcnt(6)" ::: "memory");
    LD_AF(af_b, Ac + 16384);                 // A-h1(kt)
    STAGE(B2t, row0, 1, kt+1);
    hard_barrier();
    MFMA_Q(1, af_a, bf_b);
    hard_barrier();
    // ---- ph2: Q2 = (M-h1 x N-h0) ----
    asm volatile("s_waitcnt vmcnt(4)" ::: "memory");
    STAGE(B2t, row0, 0, kt+2);
    hard_barrier();
    MFMA_Q(2, af_b, bf_a);
    hard_barrier();
    // ---- ph3: Q3 = (M-h1 x N-h1) ----
    LD_BF(bf_a, Bn);                         // B-h0(kt+1)
    LD_AF(af_a, An);                         // A-h0(kt+1)
    STAGE(Xb, col0, 0, kt+2);
    hard_barrier();
    MFMA_Q(3, af_b, bf_b);
    hard_barrier();
  }

  // ---- fused epilogue: Q/K[tok][r], V^T[b][h][d][s] = sum_n C[r*32+n][tok]*t[tok][n] ----
  asm volatile("s_waitcnt vmcnt(0)" ::: "memory");
  __syncthreads();
  short* t16 = (short*)smem;    // [3][256 tok][36] bf16
  for (int i = tid; i < 8192; i += 512){
    int tk = i >> 5, n = i & 31;
    t16[tk*36 + n]            = f2bf(tQp[(size_t)col0*32 + i]);
    t16[9216 + tk*36 + n]     = f2bf(tKp[(size_t)col0*32 + i]);
    t16[18432 + tk*36 + n]    = f2bf(tVp[(size_t)col0*32 + i]);
  }
  __syncthreads();
  int g4 = g16 << 2;
  // acc[q][m][n]: c = row0 + (q>>1)*128 + wm*64 + m*16 + g4 + e ; tok = col0 + (q&1)*128 + wn*32 + n*16 + l15
  #pragma unroll
  for (int rec=0; rec<3; rec++){
    const short* tb = t16 + rec*9216;
    #pragma unroll
    for (int q=0;q<4;q++){
      int rb = (row0 >> 5) + (q>>1)*4 + wm*2;
      #pragma unroll
      for (int n=0;n<2;n++){
        int tok = (q&1)*128 + wn*32 + n*16 + l15;     // local token 0..255
        s16x4 tlo = *(const s16x4*)(tb + tok*36 + g4);
        s16x4 thi = *(const s16x4*)(tb + tok*36 + 16 + g4);
        #pragma unroll
        for (int mp=0;mp<2;mp++){
          float p = 0.f;
          #pragma unroll
          for (int e=0;e<4;e++) p += acc[q][2*mp][n][e]   * bf2f(tlo[e]);
          #pragma unroll
          for (int e=0;e<4;e++) p += acc[q][2*mp+1][n][e] * bf2f(thi[e]);
          p += __shfl_xor(p, 16);
          p += __shfl_xor(p, 32);
          if (g16 == rec){
            int gtok = col0 + tok;
            int r = rb + mp;
            if (rec == 0)      Qb[(size_t)gtok*512 + r] = f2bf(p);
            else if (rec == 1) Kb[(size_t)gtok*512 + r] = f2bf(p);
            else Vt[(((size_t)(gtok>>11)*8 + (r>>6))*64 + (r&63))*2048 + (gtok&2047)] = f2bf(p);
          }
        }
      }
    }
  }
}

// ---------------- router: bf16-MFMA scores -> top-32 candidates -> f64 exact rescore -> top-8 ----------------
__global__ __launch_bounds__(64) void k_router(const float* __restrict__ scores,
    const float* __restrict__ X, const float* __restrict__ W,
    const float* __restrict__ rQ, const float* __restrict__ rK, const float* __restrict__ rV,
    float* __restrict__ tQ, float* __restrict__ tK, float* __restrict__ tV,
    float* __restrict__ oidx, float* __restrict__ ow){
  int token = blockIdx.x; int lane = threadIdx.x;
  const float* srow = scores + (size_t)token*512;
  float v[8];
  #pragma unroll
  for (int j=0;j<8;j++) v[j] = srow[lane + 64*j];
  int myidx = 0x7fffffff;
  #pragma unroll
  for (int k=0;k<32;k++){
    float bm = -INFINITY; int bi = 0x7fffffff;
    #pragma unroll
    for (int j=0;j<8;j++){ if (v[j] > bm) { bm = v[j]; bi = lane + 64*j; } }
    #pragma unroll
    for (int off=32; off>=1; off>>=1){
      float om = __shfl_xor(bm, off); int oi = __shfl_xor(bi, off);
      if (om > bm || (om == bm && oi < bi)) { bm = om; bi = oi; }
    }
    if (lane == k) myidx = bi;
    #pragma unroll
    for (int j=0;j<8;j++) if (lane + 64*j == bi) v[j] = -INFINITY;
  }
  float xr[16];
  {
    const float4* x4 = (const float4*)(X + (size_t)token*1024 + lane*16);
    #pragma unroll
    for (int q=0;q<4;q++){ float4 t = x4[q]; xr[q*4]=t.x; xr[q*4+1]=t.y; xr[q*4+2]=t.z; xr[q*4+3]=t.w; }
  }
  double myref = -1e300;
  #pragma unroll
  for (int c=0;c<32;c++){
    int nid = __shfl(myidx, c);
    const float4* w4 = (const float4*)(W + (size_t)nid*1024 + lane*16);
    double acc = 0.0;
    #pragma unroll
    for (int q=0;q<4;q++){
      float4 t = w4[q];
      acc += (double)xr[q*4]   * (double)t.x;
      acc += (double)xr[q*4+1] * (double)t.y;
      acc += (double)xr[q*4+2] * (double)t.z;
      acc += (double)xr[q*4+3] * (double)t.w;
    }
    #pragma unroll
    for (int off=32; off>=1; off>>=1) acc += __shfl_xor(acc, off);
    if (lane == c) myref = acc;
  }
  double mv = myref; int mi = myidx;
  double topv[8]; int topi[8];
  #pragma unroll
  for (int k=0;k<8;k++){
    double bm = mv; int bi = mi;
    #pragma unroll
    for (int off=32; off>=1; off>>=1){
      double om = __shfl_xor(bm, off); int oi = __shfl_xor(bi, off);
      if (om > bm || (om == bm && oi < bi)) { bm = om; bi = oi; }
    }
    topv[k]=bm; topi[k]=bi;
    if (mi == bi) mv = -1e300;
  }
  double mx = topv[0]; double s = 0.0; double wd[8];
  #pragma unroll
  for (int k=0;k<8;k++){ wd[k] = exp(topv[k]-mx); s += wd[k]; }
  float w[8];
  #pragma unroll
  for (int k=0;k<8;k++) w[k] = (float)(wd[k]/s);
  if (lane == 0){
    #pragma unroll
    for (int k=0;k<8;k++){ oidx[(size_t)token*8+k] = (float)topi[k]; ow[(size_t)token*8+k] = w[k]; }
  }
  int n = lane & 31;
  float aq=0.f, ak=0.f, av=0.f;
  #pragma unroll
  for (int k=0;k<8;k++){
    size_t off = (size_t)topi[k]*32 + n;
    aq += w[k]*rQ[off]; ak += w[k]*rK[off]; av += w[k]*rV[off];
  }
  float mq = aq, mk2 = ak, mvv = av;
  #pragma unroll
  for (int off=16; off>=1; off>>=1){
    mq  = fmaxf(mq,  __shfl_xor(mq, off));
    mk2 = fmaxf(mk2, __shfl_xor(mk2,off));
    mvv = fmaxf(mvv, __shfl_xor(mvv,off));
  }
  float eq = expf(aq-mq), ek = expf(ak-mk2), ev = expf(av-mvv);
  float sq = eq, sk = ek, sv = ev;
  #pragma unroll
  for (int off=16; off>=1; off>>=1){
    sq += __shfl_xor(sq,off); sk += __shfl_xor(sk,off); sv += __shfl_xor(sv,off);
  }
  if (lane < 32){
    tQ[(size_t)token*32+n] = eq/sq;
    tK[(size_t)token*32+n] = ek/sk;
    tV[(size_t)token*32+n] = ev/sv;
  }
}

// ---------------- causal flash attention: 4 waves, QBLK=64, KVBLK=64, swizzled LDS ----------------
// Vt layout: [b][h][64 d][2048 s]. Grid: 1024 blocks x 256 thr.
__global__ __launch_bounds__(256) void k_attn(const short* __restrict__ Qb, const short* __restrict__ Kb,
                                              const short* __restrict__ Vt, short* __restrict__ Ob)
{
  __shared__ char smem[40960];  // K[2][8KB] @0, Vt[2][8KB] @16384, P[4][2KB] @32768
  int tid = threadIdx.x, lane = tid & 63, wid = tid >> 6;
  int l15 = lane & 15, l7 = lane & 7, g16 = lane >> 4;
  int bid = blockIdx.x;
  int xcd = bid & 7, lid = bid >> 3;
  int work = xcd*128 + lid;              // XCD-chunked: 4 (b,h) per XCD
  int bx = 31 - (work & 31);             // big (diagonal-heavy) blocks first
  int bh = work >> 5; int h = bh & 7, b = bh >> 3;
  size_t tokbase = (size_t)b*2048;
  int q0 = bx << 6;
  int nt = bx + 1;

#define ATTN_STAGE(kt_) do{ \
  int _c = (kt_) & 1; \
  _Pragma("unroll") \
  for (int _i=0;_i<2;_i++){ \
    int _row = _i*32 + (wid<<3) + (lane>>3); \
    gload16(Kb + (tokbase + (((kt_)<<6) + _row))*512 + (h<<6) + ((l7 ^ (_row&7))<<3), \
            smem + (_c<<13) + _i*4096 + (wid<<10) + lane*16); \
    gload16(Vt + (size_t)((bh<<6) + _row)*2048 + ((kt_)<<6) + ((l7 ^ (_row&7))<<3), \
            smem + 16384 + (_c<<13) + _i*4096 + (wid<<10) + lane*16); \
  } \
}while(0)

  // Q fragments (A-operand rows = q)
  s16x8 qf[2];
  {
    const short* qp = Qb + (tokbase + q0 + wid*16 + l15)*512 + (h<<6);
    qf[0] = *(const s16x8*)(qp + g16*8);
    qf[1] = *(const s16x8*)(qp + 32 + g16*8);
  }
  f32x4 o[4]; float mrow[4], lrow[4];
  #pragma unroll
  for (int i=0;i<4;i++){
    #pragma unroll
    for (int e=0;e<4;e++) o[i][e]=0.f;
    mrow[i]=-INFINITY; lrow[i]=0.f;
  }

  ATTN_STAGE(0);
  __syncthreads();

  for (int kt = 0; kt < nt; ++kt){
    if (kt + 1 < nt) ATTN_STAGE(kt+1);
    int cur = kt & 1;
    const char* Kc = smem + (cur<<13);
    const char* Vc = smem + 16384 + (cur<<13);
    short* Pw16 = (short*)(smem + 32768 + (wid<<11));
    // ---- QK^T: S[s16] covers kv subtile s16*16..+15 ----
    f32x4 S[4];
    #pragma unroll
    for (int s16=0;s16<4;s16++){
      #pragma unroll
      for (int e=0;e<4;e++) S[s16][e] = 0.f;
      const char* kr = Kc + (s16*16 + l15)*128;
      s16x8 kf0 = *(const s16x8*)(kr + (((g16  ) ^ l7)<<4));
      s16x8 kf1 = *(const s16x8*)(kr + (((4+g16) ^ l7)<<4));
      S[s16] = __builtin_amdgcn_mfma_f32_16x16x32_bf16(qf[0], kf0, S[s16], 0,0,0);
      S[s16] = __builtin_amdgcn_mfma_f32_16x16x32_bf16(qf[1], kf1, S[s16], 0,0,0);
    }
    // ---- online softmax (per lane: q = q0+wid*16+g16*4+e, kv = s16*16+l15) ----
    bool diag = (kt == nt-1);
    #pragma unroll
    for (int e=0;e<4;e++){
      float sv0 = S[0][e]*0.125f, sv1 = S[1][e]*0.125f;
      float sv2 = S[2][e]*0.125f, sv3 = S[3][e]*0.125f;
      if (diag){
        int q_abs = q0 + wid*16 + (g16<<2) + e;
        int kvb = (kt<<6) + l15;
        if (kvb      > q_abs) sv0 = -1e30f;
        if (kvb + 16 > q_abs) sv1 = -1e30f;
        if (kvb + 32 > q_abs) sv2 = -1e30f;
        if (kvb + 48 > q_abs) sv3 = -1e30f;
      }
      float tm = fmaxf(fmaxf(sv0,sv1), fmaxf(sv2,sv3));
      #pragma unroll
      for (int off=1; off<16; off<<=1) tm = fmaxf(tm, __shfl_xor(tm, off));
      float mnew = fmaxf(mrow[e], tm);
      float alpha = expf(mrow[e] - mnew);
      mrow[e] = mnew;
      float p0 = expf(sv0-mnew), p1 = expf(sv1-mnew);
      float p2 = expf(sv2-mnew), p3 = expf(sv3-mnew);
      float ps = (p0+p1) + (p2+p3);
      #pragma unroll
      for (int off=1; off<16; off<<=1) ps += __shfl_xor(ps, off);
      lrow[e] = lrow[e]*alpha + ps;
      #pragma unroll
      for (int df=0;df<4;df++) o[df][e] *= alpha;
      int prow = (g16<<2) + e;
      int pbase = prow*64; int pr7 = prow & 7;
      int g0 = l15 >> 3, w2 = l15 & 7;
      Pw16[pbase + (((g0  ) ^ pr7)<<3) + w2] = f2bf(p0);
      Pw16[pbase + (((2+g0) ^ pr7)<<3) + w2] = f2bf(p1);
      Pw16[pbase + (((4+g0) ^ pr7)<<3) + w2] = f2bf(p2);
      Pw16[pbase + (((6+g0) ^ pr7)<<3) + w2] = f2bf(p3);
    }
    // ---- PV: o[df] += P(16q x 64kv) @ V^T(64d x 64kv)^T ----
    const char* Pb = (const char*)Pw16;
    s16x8 pf0 = *(const s16x8*)(Pb + l15*128 + (((g16  ) ^ l7)<<4));
    s16x8 pf1 = *(const s16x8*)(Pb + l15*128 + (((4+g16) ^ l7)<<4));
    #pragma unroll
    for (int df=0;df<4;df++){
      const char* vr = Vc + (df*16 + l15)*128;
      s16x8 vf0 = *(const s16x8*)(vr + (((g16  ) ^ l7)<<4));
      s16x8 vf1 = *(const s16x8*)(vr + (((4+g16) ^ l7)<<4));
      o[df] = __builtin_amdgcn_mfma_f32_16x16x32_bf16(pf0, vf0, o[df], 0,0,0);
      o[df] = __builtin_amdgcn_mfma_f32_16x16x32_bf16(pf1, vf1, o[df], 0,0,0);
    }
    __syncthreads();
  }
  #pragma unroll
  for (int df=0;df<4;df++)
    #pragma unroll
    for (int e=0;e<4;e++){
      int q = q0 + wid*16 + (g16<<2) + e;
      int d = df*16 + l15;
      Ob[(tokbase + q)*512 + (h<<6) + d] = f2bf(o[df][e] / lrow[e]);
    }
#undef ATTN_STAGE
}

extern "C" void kernel_launch(void* const* d_in, const int* in_sizes, int n_in,
                              void* d_out, int out_size, void* d_ws, size_t ws_size,
                              hipStream_t stream)
{
  const float* x     = (const float*)d_in[0];
  const float* Wrt   = (const float*)d_in[1];
  const float* rQ    = (const float*)d_in[2];
  const float* rK    = (const float*)d_in[3];
  const float* rV    = (const float*)d_in[4];
  const float* basis = (const float*)d_in[5];
  const float* Wo    = (const float*)d_in[6];
  // d_in[7] = mask (causal tril; reproduced analytically)
  float* out = (float*)d_out;
  char* ws = (char*)d_ws;
  short* B2t  = (short*)(ws + 0);          // 32 MB  [16384][1024] bf16
  short* Xb   = (short*)(ws + 33554432);   // 16 MB  [8192][1024]  bf16
  float* SC   = (float*)(ws + 50331648);   // 16 MB  [8192][512]   f32
  float* tQ   = (float*)(ws + 67108864);   // 1 MB
  float* tK   = (float*)(ws + 68157440);   // 1 MB
  float* tV   = (float*)(ws + 69206016);   // 1 MB
  short* Qb   = (short*)(ws + 70254592);   // 8 MB   [8192][512] bf16
  short* Kb   = (short*)(ws + 78643200);   // 8 MB
  short* Vt   = (short*)(ws + 87031808);   // 8 MB   [4][8][64][2048] bf16 (V transposed)
  short* Ob   = (short*)(ws + 95420416);   // 8 MB
  short* Wob  = (short*)(ws + 103809024);  // 1 MB   [1024][512] bf16
  short* Wrtb = (short*)(ws + 104857600);  // 1 MB   [512][1024] bf16
  float* oidx = out + 8388608;
  float* oww  = out + 8454144;

  hipFuncSetAttribute((const void*)k_pgemm8, hipFuncAttributeMaxDynamicSharedMemorySize, 131072);

  k_conv_bf16<<<8192, 256, 0, stream>>>(x, Xb, 2097152);
  k_conv_bf16<<<512, 256, 0, stream>>>(Wo, Wob, 131072);
  k_conv_bf16<<<512, 256, 0, stream>>>(Wrt, Wrtb, 131072);
  k_conv_basis<<<dim3(8,16,32), 256, 0, stream>>>(basis, B2t);
  // scores: SC[8192][512] = Xb @ Wrtb^T (approx, bf16)
  k_gemm_c32<<<256, 256, 0, stream>>>(Xb, Wrtb, 1024, 64, SC, 512);
  k_router<<<8192, 64, 0, stream>>>(SC, x, Wrt, rQ, rK, rV, tQ, tK, tV, oidx, oww);
  k_pgemm8<<<2048, 512, 131072, stream>>>(B2t, Xb, tQ, tK, tV, Qb, Kb, Vt);
  k_attn<<<1024, 256, 0, stream>>>(Qb, Kb, Vt, Ob);
  // out[8192][1024] = Ob @ Wob^T
  k_gemm_c32<<<512, 256, 0, stream>>>(Ob, Wob, 512, 64, out, 1024);
}